// Round 1
// baseline (1774.767 us; speedup 1.0000x reference)
//
#include <hip/hip_runtime.h>
#include <stdint.h>
#include <stddef.h>

// ---------------- problem constants ----------------
#define BB   8
#define LL   128
#define DD   768
#define HH   300
#define G4   1200     // 4*H
#define NSP  630      // number of spans
#define FFD  150
#define NZK  64       // top-k

// LSTM persistent-kernel geometry
#define WG_PER_DIR 30
#define JCH 10        // h-indices per wg
#define RWS 40        // gate rows per wg (4*JCH)

__device__ __forceinline__ float sigm(float x){ return 1.0f/(1.0f+expf(-x)); }

__device__ __forceinline__ void span_decode(int s, int& w, int& i){
  if      (s < 128){ w=1; i=s; }
  else if (s < 255){ w=2; i=s-128; }
  else if (s < 381){ w=3; i=s-255; }
  else if (s < 506){ w=4; i=s-381; }
  else             { w=5; i=s-506; }
}

__device__ __forceinline__ uint64_t shfl_xor_u64(uint64_t v, int m){
  uint32_t lo = (uint32_t)v, hi = (uint32_t)(v >> 32);
  lo = (uint32_t)__shfl_xor((int)lo, m, 64);
  hi = (uint32_t)__shfl_xor((int)hi, m, 64);
  return ((uint64_t)hi << 32) | lo;
}

// ---------------- K1: xg = Wih @ x + bih + bhh  (both dirs) ----------------
// xg layout: [dir][t][1200][8]
__global__ __launch_bounds__(256) void k_xg(
    const float* __restrict__ x,
    const float* __restrict__ WihF, const float* __restrict__ bihF, const float* __restrict__ bhhF,
    const float* __restrict__ WihB, const float* __restrict__ bihB, const float* __restrict__ bhhB,
    float* __restrict__ xg)
{
  const int dir = blockIdx.z;
  const float* Wih = dir ? WihB : WihF;
  const float* bi  = dir ? bihB : bihF;
  const float* bh  = dir ? bhhB : bhhF;
  const int r0 = blockIdx.x * 64;
  const int n0 = blockIdx.y * 64;   // n = t*8 + b
  __shared__ __align__(16) float As[16*68];
  __shared__ __align__(16) float Bs[16*68];
  const int tid = threadIdx.x;
  const int rl = tid >> 2, kq = tid & 3;
  const int tx = tid & 15, ty = tid >> 4;
  float acc[4][4] = {};
  for (int k0 = 0; k0 < DD; k0 += 16) {
    float4 a4 = make_float4(0.f,0.f,0.f,0.f);
    int ra = r0 + rl;
    if (ra < G4) a4 = *(const float4*)&Wih[ra*DD + k0 + kq*4];
    As[(kq*4+0)*68 + rl] = a4.x;
    As[(kq*4+1)*68 + rl] = a4.y;
    As[(kq*4+2)*68 + rl] = a4.z;
    As[(kq*4+3)*68 + rl] = a4.w;
    int n = n0 + rl; int tt = n >> 3, bb = n & 7;
    float4 b4 = *(const float4*)&x[(bb*LL + tt)*DD + k0 + kq*4];
    Bs[(kq*4+0)*68 + rl] = b4.x;
    Bs[(kq*4+1)*68 + rl] = b4.y;
    Bs[(kq*4+2)*68 + rl] = b4.z;
    Bs[(kq*4+3)*68 + rl] = b4.w;
    __syncthreads();
    #pragma unroll
    for (int kk = 0; kk < 16; ++kk) {
      float4 av = *(const float4*)&As[kk*68 + tx*4];
      float4 bv = *(const float4*)&Bs[kk*68 + ty*4];
      float a_[4] = {av.x,av.y,av.z,av.w};
      float b_[4] = {bv.x,bv.y,bv.z,bv.w};
      #pragma unroll
      for (int i=0;i<4;i++)
        #pragma unroll
        for (int j=0;j<4;j++)
          acc[i][j] = fmaf(a_[i], b_[j], acc[i][j]);
    }
    __syncthreads();
  }
  #pragma unroll
  for (int i=0;i<4;i++){
    int r = r0 + tx*4 + i;
    if (r >= G4) continue;
    float bias = bi[r] + bh[r];
    #pragma unroll
    for (int j=0;j<4;j++){
      int n = n0 + ty*4 + j; int tt = n>>3, bb = n&7;
      xg[((dir*LL + tt)*G4 + r)*8 + bb] = acc[i][j] + bias;
    }
  }
}

// ---------------- K2: persistent bidirectional LSTM ----------------
// 60 wg: wg/WG_PER_DIR = direction; each wg owns JCH h-indices (RWS gate rows),
// Whh slice in registers, h exchanged via global double buffer + per-dir barrier.
// hbuf layout: [parity][dir][8][320]  (pads [300..320) stay zero from memset)
__global__ __launch_bounds__(320) void k_lstm(
    const float* __restrict__ WhhF, const float* __restrict__ WhhB,
    const float* __restrict__ xg,
    float* __restrict__ hbuf,
    float* __restrict__ out,            // [b][t][600]
    unsigned int* __restrict__ ctr)     // ctr[0], ctr[32] (128B apart)
{
  const int wg  = blockIdx.x;
  const int dir = wg / WG_PER_DIR;
  const int wid = wg - dir*WG_PER_DIR;
  const int j0  = wid * JCH;
  const float* Whh = dir ? WhhB : WhhF;
  unsigned int* myctr = ctr + dir*32;

  __shared__ __align__(16) float hls[8*320];
  __shared__ float parts[RWS*8*10];
  __shared__ float gls[RWS*8];
  __shared__ float cst[JCH*8];

  const int tid = threadIdx.x;
  const int r = tid >> 3;           // 0..39 gate-row slot
  const int s = tid & 7;            // k-segment 0..7 (40 floats each)
  const int gate = r / 10, jj = r - gate*10;
  const int Rabs = gate*HH + j0 + jj;

  // register-resident Whh slice: 40 floats (10 float4) per thread
  float4 w4[10];
  #pragma unroll
  for (int q=0;q<10;q++){
    int k = s*40 + q*4;
    if (k + 3 < HH) w4[q] = *(const float4*)&Whh[Rabs*HH + k];
    else            w4[q] = make_float4(0.f,0.f,0.f,0.f);
  }
  if (tid < JCH*8) cst[tid] = 0.f;

  for (int t = 0; t < LL; ++t) {
    const int tOrig = dir ? (LL-1 - t) : t;
    // stage A: h_prev -> LDS (full [8][320], pads are zero)
    {
      const float4* src = (const float4*)&hbuf[((size_t)(t&1)*2 + dir)*2560];
      float4* dst = (float4*)hls;
      dst[tid*2]   = src[tid*2];
      dst[tid*2+1] = src[tid*2+1];
    }
    __syncthreads();
    // stage B: partial dot products
    {
      const float4* h4 = (const float4*)hls;
      #pragma unroll
      for (int b=0;b<8;b++){
        const float4* hb = h4 + b*80 + s*10;
        float ax=0.f, ay=0.f, az=0.f, aw=0.f;
        #pragma unroll
        for (int q=0;q<10;q++){
          float4 hv = hb[q];
          ax = fmaf(w4[q].x, hv.x, ax);
          ay = fmaf(w4[q].y, hv.y, ay);
          az = fmaf(w4[q].z, hv.z, az);
          aw = fmaf(w4[q].w, hv.w, aw);
        }
        parts[((r*8) + b)*10 + s] = (ax+ay)+(az+aw);
      }
    }
    __syncthreads();
    // stage C: reduce segments + add xg -> gates   (tid == r2*8+b2)
    {
      float g = 0.f;
      const float* pp = &parts[tid*10];
      #pragma unroll
      for (int q=0;q<8;q++) g += pp[q];
      g += xg[((size_t)(dir*LL + tOrig)*G4 + Rabs)*8 + (tid & 7)];
      gls[tid] = g;
    }
    __syncthreads();
    // stage D: cell update (80 threads: j x b)
    if (tid < JCH*8) {
      int j = tid >> 3, b = tid & 7;
      float ig = sigm(gls[(      j)*8 + b]);
      float fg = sigm(gls[(10  + j)*8 + b]);
      float gg = tanhf(gls[(20 + j)*8 + b]);
      float og = sigm(gls[(30 + j)*8 + b]);
      float c  = fg * cst[tid] + ig * gg;
      cst[tid] = c;
      float h  = og * tanhf(c);
      hbuf[((size_t)(((t+1)&1)*2 + dir))*2560 + b*320 + j0 + j] = h;
      out[((size_t)(b*LL + tOrig))*600 + dir*HH + j0 + j] = h;
    }
    __syncthreads();
    // stage E: inter-wg barrier (release/acquire, device scope)
    if (t < LL-1) {
      if (tid == 0) {
        __threadfence();
        __hip_atomic_fetch_add(myctr, 1u, __ATOMIC_RELEASE, __HIP_MEMORY_SCOPE_AGENT);
        const unsigned target = (unsigned)(WG_PER_DIR*(t+1));
        while (__hip_atomic_load(myctr, __ATOMIC_ACQUIRE, __HIP_MEMORY_SCOPE_AGENT) < target)
          __builtin_amdgcn_s_sleep(1);
        __threadfence();
      }
      __syncthreads();
    }
  }
}

// ---------------- K3a: U/V partial span projections ----------------
// UV[row][half*150+n] = sum_k sw1[n][half*600+k] * out[row][k],  row = b*128+l
__global__ __launch_bounds__(320) void k_uv(
    const float* __restrict__ out, const float* __restrict__ sw1, float* __restrict__ UV)
{
  const int half = blockIdx.z;
  const int row0 = blockIdx.x * 32;
  __shared__ float As[16*36];
  __shared__ __align__(16) float Wt[16*172];
  const int tid = threadIdx.x;
  const int pg = tid / 20, ng = tid - (tid/20)*20;
  float acc[2][8] = {};
  for (int k0 = 0; k0 < 600; k0 += 16) {
    for (int idx = tid; idx < 512; idx += 320) {
      int p = idx >> 4, kk = idx & 15;
      int k = k0 + kk;
      As[kk*36 + p] = (k < 600) ? out[(row0 + p)*600 + k] : 0.f;
    }
    for (int idx = tid; idx < 16*160; idx += 320) {
      int n = idx >> 4, kk = idx & 15;
      int k = k0 + kk;
      Wt[kk*172 + n] = (n < FFD && k < 600) ? sw1[n*1220 + half*600 + k] : 0.f;
    }
    __syncthreads();
    #pragma unroll
    for (int kk=0;kk<16;kk++){
      float2 a2 = *(const float2*)&As[kk*36 + pg*2];
      float4 w0 = *(const float4*)&Wt[kk*172 + ng*8];
      float4 w1 = *(const float4*)&Wt[kk*172 + ng*8 + 4];
      float a_[2] = {a2.x, a2.y};
      float w_[8] = {w0.x,w0.y,w0.z,w0.w,w1.x,w1.y,w1.z,w1.w};
      #pragma unroll
      for (int i=0;i<2;i++)
        #pragma unroll
        for (int j=0;j<8;j++)
          acc[i][j] = fmaf(a_[i], w_[j], acc[i][j]);
    }
    __syncthreads();
  }
  #pragma unroll
  for (int i=0;i<2;i++){
    int row = row0 + pg*2 + i;
    #pragma unroll
    for (int j=0;j<8;j++){
      int n = ng*8 + j;
      if (n < FFD) UV[row*300 + half*FFD + n] = acc[i][j];
    }
  }
}

// ---------------- K3w: width-embedding partial (tiny) ----------------
__global__ __launch_bounds__(160) void k_wconst(
    const float* __restrict__ sw1, const float* __restrict__ wemb, float* __restrict__ wcst)
{
  int w = blockIdx.x, n = threadIdx.x;
  if (n >= FFD) return;
  float a = 0.f;
  for (int k=0;k<20;k++) a = fmaf(sw1[n*1220 + 1200 + k], wemb[w*20 + k], a);
  wcst[w*FFD + n] = a;
}

// ---------------- K5d: distance-embedding partial ----------------
__global__ __launch_bounds__(160) void k_zd(
    const float* __restrict__ pw1, const float* __restrict__ demb, float* __restrict__ Zd)
{
  int d = blockIdx.x, n = threadIdx.x;
  if (n >= FFD) return;
  float a = 0.f;
  for (int k=0;k<128;k++) a = fmaf(pw1[n*2568 + 2440 + k], demb[d*128 + k], a);
  Zd[d*FFD + n] = a;
}

// ---------------- K3b: span head (z1 combine -> layer2 -> layer3 -> softmax) ----------------
__global__ __launch_bounds__(320) void k_spanhead(
    const float* __restrict__ UV, const float* __restrict__ wcst,
    const float* __restrict__ sb1,
    const float* __restrict__ sw2, const float* __restrict__ sb2,
    const float* __restrict__ sw3, const float* __restrict__ sb3,
    float* __restrict__ sp)
{
  const int b  = blockIdx.y;
  const int s0 = blockIdx.x * 64;
  __shared__ __align__(16) float z1T[160*68];
  __shared__ __align__(16) float z2T[160*68];
  __shared__ __align__(16) float Wt[16*172];
  __shared__ int sI[64], sJ[64], sW[64];
  const int tid = threadIdx.x;
  if (tid < 64) {
    int s = s0 + tid; int w = 1, i0 = 0;
    if (s < NSP) span_decode(s, w, i0);
    sI[tid] = i0; sJ[tid] = i0 + w - 1; sW[tid] = w;
  }
  __syncthreads();
  for (int idx = tid; idx < 64*160; idx += 320) {
    int p = idx / 160, k = idx - p*160;
    float v = 0.f;
    if (k < FFD && (s0 + p) < NSP) {
      v = UV[(b*LL + sI[p])*300 + k] + UV[(b*LL + sJ[p])*300 + FFD + k]
        + wcst[sW[p]*FFD + k] + sb1[k];
      v = fmaxf(v, 0.f);
    }
    z1T[k*68 + p] = v;
  }
  const int pg = tid / 20, ng = tid - (tid/20)*20;
  float acc[4][8] = {};
  for (int kt = 0; kt < 10; ++kt) {
    __syncthreads();
    for (int idx = tid; idx < 16*160; idx += 320) {
      int n = idx >> 4, kk = idx & 15;
      int k = kt*16 + kk;
      Wt[kk*172 + n] = (n < FFD && k < FFD) ? sw2[n*FFD + k] : 0.f;
    }
    __syncthreads();
    #pragma unroll
    for (int kk = 0; kk < 16; ++kk) {
      float4 a4 = *(const float4*)&z1T[(kt*16+kk)*68 + pg*4];
      float4 w0 = *(const float4*)&Wt[kk*172 + ng*8];
      float4 w1 = *(const float4*)&Wt[kk*172 + ng*8 + 4];
      float a_[4] = {a4.x,a4.y,a4.z,a4.w};
      float w_[8] = {w0.x,w0.y,w0.z,w0.w,w1.x,w1.y,w1.z,w1.w};
      #pragma unroll
      for (int i=0;i<4;i++)
        #pragma unroll
        for (int j=0;j<8;j++)
          acc[i][j] = fmaf(a_[i], w_[j], acc[i][j]);
    }
  }
  __syncthreads();
  #pragma unroll
  for (int j=0;j<8;j++){
    int n = ng*8 + j;
    float bn = (n < FFD) ? sb2[n] : 0.f;
    #pragma unroll
    for (int i=0;i<4;i++){
      float v = (n < FFD) ? fmaxf(acc[i][j] + bn, 0.f) : 0.f;
      z2T[n*68 + pg*4 + i] = v;
    }
  }
  __syncthreads();
  if (tid < 64 && (s0 + tid) < NSP) {
    int p = tid;
    float z[3];
    #pragma unroll
    for (int c=0;c<3;c++){
      float a = sb3[c];
      for (int k=0;k<FFD;k++) a = fmaf(z2T[k*68 + p], sw3[c*FFD + k], a);
      z[c] = a;
    }
    float m = fmaxf(z[0], fmaxf(z[1], z[2]));
    float e0 = expf(z[0]-m), e1 = expf(z[1]-m), e2 = expf(z[2]-m);
    float inv = 1.f/(e0+e1+e2);
    int s = s0 + p;
    sp[(b*NSP + s)*3 + 0] = e0*inv;
    sp[(b*NSP + s)*3 + 1] = e1*inv;
    sp[(b*NSP + s)*3 + 2] = e2*inv;
  }
}

// ---------------- K4: deterministic top-64 (ties -> smaller index, like lax.top_k) ----------------
__global__ __launch_bounds__(64) void k_topk(
    const float* __restrict__ sp, float* __restrict__ outT, float* __restrict__ outO,
    int* __restrict__ idxw)
{
  const int cls = blockIdx.x >> 3;   // 0: aspect(col1), 1: opinion(col2)
  const int b   = blockIdx.x & 7;
  const int lane = threadIdx.x;
  uint64_t key[10];
  #pragma unroll
  for (int q=0;q<10;q++){
    int s = lane + q*64;
    uint32_t bits = 0u;
    if (s < NSP) bits = __float_as_uint(sp[(b*NSP + s)*3 + 1 + cls]);
    key[q] = ((uint64_t)bits << 32) | (uint32_t)(1023 - s);
  }
  float* dst = cls ? outO : outT;
  for (int r = 0; r < NZK; ++r) {
    uint64_t best = key[0];
    #pragma unroll
    for (int q=1;q<10;q++) best = key[q] > best ? key[q] : best;
    #pragma unroll
    for (int off = 32; off > 0; off >>= 1) {
      uint64_t o = shfl_xor_u64(best, off);
      best = o > best ? o : best;
    }
    int sWin = 1023 - (int)(best & 0xFFFFFFFFu);
    if ((sWin & 63) == lane) {
      int qw = sWin >> 6;
      #pragma unroll
      for (int q=0;q<10;q++) if (q == qw) key[q] = 0;
    }
    if (lane == 0) {
      dst[b*NZK + r] = (float)sWin;
      idxw[cls*512 + b*NZK + r] = sWin;
    }
  }
}

// ---------------- K5a: Zt/Zo partial pair projections over selected spans ----------------
// slot = cls*512 + b*64 + rank ; ZTO[slot][150] = pw1[:, cls*1220 : +1220] @ span_vec(slot)
__global__ __launch_bounds__(320) void k_zto(
    const float* __restrict__ out, const float* __restrict__ wemb,
    const float* __restrict__ pw1, const int* __restrict__ idxw,
    float* __restrict__ ZTO)
{
  const int wg = blockIdx.x;
  const int cls = wg >> 5;
  const int rem = wg & 31;
  const int b = rem >> 2;
  const int i0 = (rem & 3) * 16;
  __shared__ float As[16*20];
  __shared__ __align__(16) float Wt[16*172];
  __shared__ int sI[16], sJ[16], sW[16];
  const int tid = threadIdx.x;
  if (tid < 16) {
    int S = idxw[cls*512 + b*64 + i0 + tid];
    int w, i_; span_decode(S, w, i_);
    sI[tid] = i_; sJ[tid] = i_ + w - 1; sW[tid] = w;
  }
  const int pg = tid / 20, ng = tid - (tid/20)*20;
  float acc[8] = {};
  __syncthreads();
  for (int k0 = 0; k0 < 1232; k0 += 16) {
    if (tid < 256) {
      int p = tid >> 4, kk = tid & 15;
      int k = k0 + kk;
      float v = 0.f;
      if      (k < 600)  v = out[(b*LL + sI[p])*600 + k];
      else if (k < 1200) v = out[(b*LL + sJ[p])*600 + (k - 600)];
      else if (k < 1220) v = wemb[sW[p]*20 + (k - 1200)];
      As[kk*20 + p] = v;
    }
    for (int idx = tid; idx < 16*160; idx += 320) {
      int n = idx >> 4, kk = idx & 15;
      int k = k0 + kk;
      Wt[kk*172 + n] = (n < FFD && k < 1220) ? pw1[n*2568 + cls*1220 + k] : 0.f;
    }
    __syncthreads();
    #pragma unroll
    for (int kk=0;kk<16;kk++){
      float a = As[kk*20 + pg];
      float4 w0 = *(const float4*)&Wt[kk*172 + ng*8];
      float4 w1 = *(const float4*)&Wt[kk*172 + ng*8 + 4];
      acc[0] = fmaf(a, w0.x, acc[0]);
      acc[1] = fmaf(a, w0.y, acc[1]);
      acc[2] = fmaf(a, w0.z, acc[2]);
      acc[3] = fmaf(a, w0.w, acc[3]);
      acc[4] = fmaf(a, w1.x, acc[4]);
      acc[5] = fmaf(a, w1.y, acc[5]);
      acc[6] = fmaf(a, w1.z, acc[6]);
      acc[7] = fmaf(a, w1.w, acc[7]);
    }
    __syncthreads();
  }
  #pragma unroll
  for (int j=0;j<8;j++){
    int n = ng*8 + j;
    if (n < FFD) ZTO[(cls*512 + b*64 + i0 + pg)*FFD + n] = acc[j];
  }
}

// ---------------- K5b: pair head ----------------
__global__ __launch_bounds__(320) void k_pairhead(
    const float* __restrict__ ZTO, const float* __restrict__ Zd,
    const float* __restrict__ pb1,
    const float* __restrict__ pw2, const float* __restrict__ pb2,
    const float* __restrict__ pw3, const float* __restrict__ pb3,
    const int* __restrict__ idxw,
    float* __restrict__ cp)
{
  const int b  = blockIdx.y;
  const int ti = blockIdx.x;
  __shared__ __align__(16) float z1T[160*68];
  __shared__ __align__(16) float z2T[160*68];
  __shared__ __align__(16) float Wt[16*172];
  __shared__ int oDist[64];
  const int tid = threadIdx.x;
  const int tS = idxw[b*64 + ti];
  int wT, iT; span_decode(tS, wT, iT);
  const int aT = iT, bT = iT + wT - 1;
  if (tid < 64) {
    int oS = idxw[512 + b*64 + tid];
    int wO, iO; span_decode(oS, wO, iO);
    int d1 = bT - iO;            if (d1 < 0) d1 = -d1;
    int d2 = aT - (iO + wO - 1); if (d2 < 0) d2 = -d2;
    oDist[tid] = d1 < d2 ? d1 : d2;
  }
  __syncthreads();
  const float* ZtRow = ZTO + (b*64 + ti)*FFD;
  for (int idx = tid; idx < 64*160; idx += 320) {
    int p = idx / 160, k = idx - p*160;
    float v = 0.f;
    if (k < FFD) {
      v = ZtRow[k] + ZTO[(512 + b*64 + p)*FFD + k] + Zd[oDist[p]*FFD + k] + pb1[k];
      v = fmaxf(v, 0.f);
    }
    z1T[k*68 + p] = v;
  }
  const int pg = tid / 20, ng = tid - (tid/20)*20;
  float acc[4][8] = {};
  for (int kt = 0; kt < 10; ++kt) {
    __syncthreads();
    for (int idx = tid; idx < 16*160; idx += 320) {
      int n = idx >> 4, kk = idx & 15;
      int k = kt*16 + kk;
      Wt[kk*172 + n] = (n < FFD && k < FFD) ? pw2[n*FFD + k] : 0.f;
    }
    __syncthreads();
    #pragma unroll
    for (int kk = 0; kk < 16; ++kk) {
      float4 a4 = *(const float4*)&z1T[(kt*16+kk)*68 + pg*4];
      float4 w0 = *(const float4*)&Wt[kk*172 + ng*8];
      float4 w1 = *(const float4*)&Wt[kk*172 + ng*8 + 4];
      float a_[4] = {a4.x,a4.y,a4.z,a4.w};
      float w_[8] = {w0.x,w0.y,w0.z,w0.w,w1.x,w1.y,w1.z,w1.w};
      #pragma unroll
      for (int i=0;i<4;i++)
        #pragma unroll
        for (int j=0;j<8;j++)
          acc[i][j] = fmaf(a_[i], w_[j], acc[i][j]);
    }
  }
  __syncthreads();
  #pragma unroll
  for (int j=0;j<8;j++){
    int n = ng*8 + j;
    float bn = (n < FFD) ? pb2[n] : 0.f;
    #pragma unroll
    for (int i=0;i<4;i++){
      float v = (n < FFD) ? fmaxf(acc[i][j] + bn, 0.f) : 0.f;
      z2T[n*68 + pg*4 + i] = v;
    }
  }
  __syncthreads();
  if (tid < 64) {
    int p = tid;
    float z[4];
    #pragma unroll
    for (int c=0;c<4;c++){
      float a = pb3[c];
      for (int k=0;k<FFD;k++) a = fmaf(z2T[k*68 + p], pw3[c*FFD + k], a);
      z[c] = a;
    }
    float m = fmaxf(fmaxf(z[0],z[1]), fmaxf(z[2],z[3]));
    float e0 = expf(z[0]-m), e1 = expf(z[1]-m), e2 = expf(z[2]-m), e3 = expf(z[3]-m);
    float inv = 1.f/(e0+e1+e2+e3);
    float4 o4 = make_float4(e0*inv, e1*inv, e2*inv, e3*inv);
    *(float4*)&cp[(size_t)((b*4096 + ti*64 + p))*4] = o4;
  }
}

// ---------------- launch ----------------
extern "C" void kernel_launch(void* const* d_in, const int* in_sizes, int n_in,
                              void* d_out, int out_size, void* d_ws, size_t ws_size,
                              hipStream_t stream) {
  const float* x    = (const float*)d_in[0];
  const float* WihF = (const float*)d_in[1];
  const float* WhhF = (const float*)d_in[2];
  const float* bihF = (const float*)d_in[3];
  const float* bhhF = (const float*)d_in[4];
  const float* WihB = (const float*)d_in[5];
  const float* WhhB = (const float*)d_in[6];
  const float* bihB = (const float*)d_in[7];
  const float* bhhB = (const float*)d_in[8];
  const float* wemb = (const float*)d_in[9];
  const float* demb = (const float*)d_in[10];
  const float* sw1  = (const float*)d_in[11];
  const float* sb1  = (const float*)d_in[12];
  const float* sw2  = (const float*)d_in[13];
  const float* sb2  = (const float*)d_in[14];
  const float* sw3  = (const float*)d_in[15];
  const float* sb3  = (const float*)d_in[16];
  const float* pw1  = (const float*)d_in[17];
  const float* pb1  = (const float*)d_in[18];
  const float* pw2  = (const float*)d_in[19];
  const float* pb2  = (const float*)d_in[20];
  const float* pw3  = (const float*)d_in[21];
  const float* pb3  = (const float*)d_in[22];

  uint8_t* wsb = (uint8_t*)d_ws;
  unsigned int* ctr = (unsigned int*)wsb;          // 2 counters, 128B apart
  float* hbuf = (float*)(wsb + 4096);              // [2][2][8][320] = 10240 f
  float* xg   = (float*)(wsb + 131072);            // [2][128][1200][8] = 2457600 f
  float* outh = xg   + 2457600;                    // [8][128][600]     = 614400 f
  float* UV   = outh + 614400;                     // [1024][300]       = 307200 f
  float* wcst = UV   + 307200;                     // [6][150]          = 900 f
  float* Zd   = wcst + 900;                        // [256][150]        = 38400 f
  float* ZTO  = Zd   + 38400;                      // [1024][150]       = 153600 f
  int*  idxw  = (int*)(ZTO + 153600);              // [2][8][64]        = 1024 i
  // total ~14.4 MB of d_ws used

  float* o   = (float*)d_out;
  float* spO = o;              // [8][630][3]  = 15120
  float* cpO = o + 15120;      // [8][4096][4] = 131072
  float* tO  = o + 146192;     // [8][64]
  float* oO  = o + 146704;     // [8][64]

  // zero barrier counters + h ping-pong (pads must be zero)
  hipMemsetAsync(d_ws, 0, 131072, stream);

  k_xg      <<<dim3(19,16,2), 256, 0, stream>>>(x, WihF, bihF, bhhF, WihB, bihB, bhhB, xg);
  k_lstm    <<<dim3(2*WG_PER_DIR), 320, 0, stream>>>(WhhF, WhhB, xg, hbuf, outh, ctr);
  k_uv      <<<dim3(32,1,2), 320, 0, stream>>>(outh, sw1, UV);
  k_wconst  <<<dim3(6),   160, 0, stream>>>(sw1, wemb, wcst);
  k_zd      <<<dim3(256), 160, 0, stream>>>(pw1, demb, Zd);
  k_spanhead<<<dim3(10,8), 320, 0, stream>>>(UV, wcst, sb1, sw2, sb2, sw3, sb3, spO);
  k_topk    <<<dim3(16),  64, 0, stream>>>(spO, tO, oO, idxw);
  k_zto     <<<dim3(64),  320, 0, stream>>>(outh, wemb, pw1, idxw, ZTO);
  k_pairhead<<<dim3(64,8), 320, 0, stream>>>(ZTO, Zd, pb1, pw2, pb2, pw3, pb3, idxw, cpO);
}

// Round 2
// 1493.017 us; speedup vs baseline: 1.1887x; 1.1887x over previous
//
#include <hip/hip_runtime.h>
#include <stdint.h>
#include <stddef.h>

// ---------------- problem constants ----------------
#define BB   8
#define LL   128
#define DD   768
#define HH   300
#define G4   1200     // 4*H
#define NSP  630      // number of spans
#define FFD  150
#define NZK  64       // top-k

// LSTM persistent-kernel geometry
#define WG_PER_DIR 30
#define JCH 10        // h-indices per wg
#define RWS 40        // gate rows per wg (4*JCH)

__device__ __forceinline__ float sigm(float x){ return 1.0f/(1.0f+expf(-x)); }

__device__ __forceinline__ void span_decode(int s, int& w, int& i){
  if      (s < 128){ w=1; i=s; }
  else if (s < 255){ w=2; i=s-128; }
  else if (s < 381){ w=3; i=s-255; }
  else if (s < 506){ w=4; i=s-381; }
  else             { w=5; i=s-506; }
}

__device__ __forceinline__ uint64_t shfl_xor_u64(uint64_t v, int m){
  uint32_t lo = (uint32_t)v, hi = (uint32_t)(v >> 32);
  lo = (uint32_t)__shfl_xor((int)lo, m, 64);
  hi = (uint32_t)__shfl_xor((int)hi, m, 64);
  return ((uint64_t)hi << 32) | lo;
}

// ---------------- K1: xg = Wih @ x + bih + bhh  (both dirs) ----------------
// xg layout: [dir][t][1200][8].  Also zeroes the LSTM done-flags via sc1
// (agent-scope) stores so k_lstm's coherent polls see real zeros.
__global__ __launch_bounds__(256) void k_xg(
    const float* __restrict__ x,
    const float* __restrict__ WihF, const float* __restrict__ bihF, const float* __restrict__ bhhF,
    const float* __restrict__ WihB, const float* __restrict__ bihB, const float* __restrict__ bhhB,
    float* __restrict__ xg, unsigned int* __restrict__ flags)
{
  if (blockIdx.x==0 && blockIdx.y==0 && blockIdx.z==0 && threadIdx.x < 60) {
    __hip_atomic_store(&flags[threadIdx.x*32], 0u, __ATOMIC_RELAXED, __HIP_MEMORY_SCOPE_AGENT);
  }
  const int dir = blockIdx.z;
  const float* Wih = dir ? WihB : WihF;
  const float* bi  = dir ? bihB : bihF;
  const float* bh  = dir ? bhhB : bhhF;
  const int r0 = blockIdx.x * 64;
  const int n0 = blockIdx.y * 64;   // n = t*8 + b
  __shared__ __align__(16) float As[16*68];
  __shared__ __align__(16) float Bs[16*68];
  const int tid = threadIdx.x;
  const int rl = tid >> 2, kq = tid & 3;
  const int tx = tid & 15, ty = tid >> 4;
  float acc[4][4] = {};
  for (int k0 = 0; k0 < DD; k0 += 16) {
    float4 a4 = make_float4(0.f,0.f,0.f,0.f);
    int ra = r0 + rl;
    if (ra < G4) a4 = *(const float4*)&Wih[ra*DD + k0 + kq*4];
    As[(kq*4+0)*68 + rl] = a4.x;
    As[(kq*4+1)*68 + rl] = a4.y;
    As[(kq*4+2)*68 + rl] = a4.z;
    As[(kq*4+3)*68 + rl] = a4.w;
    int n = n0 + rl; int tt = n >> 3, bb = n & 7;
    float4 b4 = *(const float4*)&x[(bb*LL + tt)*DD + k0 + kq*4];
    Bs[(kq*4+0)*68 + rl] = b4.x;
    Bs[(kq*4+1)*68 + rl] = b4.y;
    Bs[(kq*4+2)*68 + rl] = b4.z;
    Bs[(kq*4+3)*68 + rl] = b4.w;
    __syncthreads();
    #pragma unroll
    for (int kk = 0; kk < 16; ++kk) {
      float4 av = *(const float4*)&As[kk*68 + tx*4];
      float4 bv = *(const float4*)&Bs[kk*68 + ty*4];
      float a_[4] = {av.x,av.y,av.z,av.w};
      float b_[4] = {bv.x,bv.y,bv.z,bv.w};
      #pragma unroll
      for (int i=0;i<4;i++)
        #pragma unroll
        for (int j=0;j<4;j++)
          acc[i][j] = fmaf(a_[i], b_[j], acc[i][j]);
    }
    __syncthreads();
  }
  #pragma unroll
  for (int i=0;i<4;i++){
    int r = r0 + tx*4 + i;
    if (r >= G4) continue;
    float bias = bi[r] + bh[r];
    #pragma unroll
    for (int j=0;j<4;j++){
      int n = n0 + ty*4 + j; int tt = n>>3, bb = n&7;
      xg[((dir*LL + tt)*G4 + r)*8 + bb] = acc[i][j] + bias;
    }
  }
}

// ---------------- K2: persistent bidirectional LSTM ----------------
// 60 wg; each owns JCH h-indices (RWS gate rows), Whh slice in registers.
// h exchange: relaxed AGENT-scope (sc1) atomics only — per-access coherence,
// NO C++ fences (those emit full-L2 wbl2/inv per step = the round-1 7.5us/step).
// Sync: per-WG own-slot flag (128B apart), posted after s_waitcnt+barrier;
// 30 lanes poll 30 flag lines. hbuf: [parity][dir][8][320]; t==0 h comes from
// in-kernel zeros (no memset dependency).
__global__ __launch_bounds__(320) void k_lstm(
    const float* __restrict__ WhhF, const float* __restrict__ WhhB,
    const float* __restrict__ xg,
    float* __restrict__ hbuf,
    float* __restrict__ out,            // [b][t][600]
    unsigned int* __restrict__ flags)   // [60] slots, stride 32 ints
{
  const int wg  = blockIdx.x;
  const int dir = wg / WG_PER_DIR;
  const int wid = wg - dir*WG_PER_DIR;
  const int j0  = wid * JCH;
  const float* Whh = dir ? WhhB : WhhF;

  __shared__ __align__(16) float hls[8*320];
  __shared__ float parts[RWS*8*11];
  __shared__ float gls[RWS*8];
  __shared__ float cst[JCH*8];

  const int tid = threadIdx.x;
  const int r = tid >> 3;           // 0..39 gate-row slot
  const int s = tid & 7;            // k-segment 0..7 (40 floats each)
  const int gate = r / 10, jj = r - gate*10;
  const int Rabs = gate*HH + j0 + jj;

  // register-resident Whh slice: 40 floats (10 float4) per thread
  float4 w4[10];
  #pragma unroll
  for (int q=0;q<10;q++){
    int k = s*40 + q*4;
    if (k + 3 < HH) w4[q] = *(const float4*)&Whh[Rabs*HH + k];
    else            w4[q] = make_float4(0.f,0.f,0.f,0.f);
  }
  if (tid < JCH*8) cst[tid] = 0.f;

  for (int t = 0; t < LL; ++t) {
    const int tOrig = dir ? (LL-1 - t) : t;
    // stage A: h_prev -> LDS (sc1 coherent loads; zeros at t==0)
    if (t == 0) {
      #pragma unroll
      for (int k=0;k<8;k++) hls[tid + k*320] = 0.f;
    } else {
      const float* src = &hbuf[((size_t)(t&1)*2 + dir)*2560];
      #pragma unroll
      for (int k=0;k<8;k++)
        hls[tid + k*320] =
          __hip_atomic_load(&src[tid + k*320], __ATOMIC_RELAXED, __HIP_MEMORY_SCOPE_AGENT);
    }
    __syncthreads();
    // stage B: partial dot products
    {
      const float4* h4 = (const float4*)hls;
      #pragma unroll
      for (int b=0;b<8;b++){
        const float4* hb = h4 + b*80 + s*10;
        float ax=0.f, ay=0.f, az=0.f, aw=0.f;
        #pragma unroll
        for (int q=0;q<10;q++){
          float4 hv = hb[q];
          ax = fmaf(w4[q].x, hv.x, ax);
          ay = fmaf(w4[q].y, hv.y, ay);
          az = fmaf(w4[q].z, hv.z, az);
          aw = fmaf(w4[q].w, hv.w, aw);
        }
        parts[((r*8) + b)*11 + s] = (ax+ay)+(az+aw);
      }
    }
    __syncthreads();
    // stage C: reduce segments + add xg -> gates   (tid == r2*8+b2)
    {
      float g = 0.f;
      const float* pp = &parts[tid*11];
      #pragma unroll
      for (int q=0;q<8;q++) g += pp[q];
      g += xg[((size_t)(dir*LL + tOrig)*G4 + Rabs)*8 + (tid & 7)];
      gls[tid] = g;
    }
    __syncthreads();
    // stage D: cell update (80 threads: j x b); h store is sc1
    if (tid < JCH*8) {
      int j = tid >> 3, b = tid & 7;
      float ig = sigm(gls[(      j)*8 + b]);
      float fg = sigm(gls[(10  + j)*8 + b]);
      float gg = tanhf(gls[(20 + j)*8 + b]);
      float og = sigm(gls[(30 + j)*8 + b]);
      float c  = fg * cst[tid] + ig * gg;
      cst[tid] = c;
      float h  = og * tanhf(c);
      __hip_atomic_store(&hbuf[((size_t)(((t+1)&1)*2 + dir))*2560 + b*320 + j0 + j], h,
                         __ATOMIC_RELAXED, __HIP_MEMORY_SCOPE_AGENT);
      out[((size_t)(b*LL + tOrig))*600 + dir*HH + j0 + j] = h;
    }
    // drain every wave's stores, then the WG-wide barrier
    asm volatile("s_waitcnt vmcnt(0)" ::: "memory");
    __syncthreads();
    // stage E: post own flag, poll all 30 peer flags (separate cachelines)
    if (t < LL-1) {
      if (tid == 0)
        __hip_atomic_store(&flags[(dir*WG_PER_DIR + wid)*32], (unsigned)(t+1),
                           __ATOMIC_RELAXED, __HIP_MEMORY_SCOPE_AGENT);
      if (tid < WG_PER_DIR) {
        while (__hip_atomic_load(&flags[(dir*WG_PER_DIR + tid)*32],
                                 __ATOMIC_RELAXED, __HIP_MEMORY_SCOPE_AGENT) < (unsigned)(t+1))
          __builtin_amdgcn_s_sleep(1);
      }
      __syncthreads();
    }
  }
}

// ---------------- K3a: U/V partial span projections ----------------
// UV[row][half*150+n] = sum_k sw1[n][half*600+k] * out[row][k],  row = b*128+l
__global__ __launch_bounds__(320) void k_uv(
    const float* __restrict__ out, const float* __restrict__ sw1, float* __restrict__ UV)
{
  const int half = blockIdx.z;
  const int row0 = blockIdx.x * 32;
  __shared__ float As[16*36];
  __shared__ __align__(16) float Wt[16*172];
  const int tid = threadIdx.x;
  const int pg = tid / 20, ng = tid - (tid/20)*20;
  float acc[2][8] = {};
  for (int k0 = 0; k0 < 600; k0 += 16) {
    for (int idx = tid; idx < 512; idx += 320) {
      int p = idx >> 4, kk = idx & 15;
      int k = k0 + kk;
      As[kk*36 + p] = (k < 600) ? out[(row0 + p)*600 + k] : 0.f;
    }
    for (int idx = tid; idx < 16*160; idx += 320) {
      int n = idx >> 4, kk = idx & 15;
      int k = k0 + kk;
      Wt[kk*172 + n] = (n < FFD && k < 600) ? sw1[n*1220 + half*600 + k] : 0.f;
    }
    __syncthreads();
    #pragma unroll
    for (int kk=0;kk<16;kk++){
      float2 a2 = *(const float2*)&As[kk*36 + pg*2];
      float4 w0 = *(const float4*)&Wt[kk*172 + ng*8];
      float4 w1 = *(const float4*)&Wt[kk*172 + ng*8 + 4];
      float a_[2] = {a2.x, a2.y};
      float w_[8] = {w0.x,w0.y,w0.z,w0.w,w1.x,w1.y,w1.z,w1.w};
      #pragma unroll
      for (int i=0;i<2;i++)
        #pragma unroll
        for (int j=0;j<8;j++)
          acc[i][j] = fmaf(a_[i], w_[j], acc[i][j]);
    }
    __syncthreads();
  }
  #pragma unroll
  for (int i=0;i<2;i++){
    int row = row0 + pg*2 + i;
    #pragma unroll
    for (int j=0;j<8;j++){
      int n = ng*8 + j;
      if (n < FFD) UV[row*300 + half*FFD + n] = acc[i][j];
    }
  }
}

// ---------------- K3w: width-embedding partial (tiny) ----------------
__global__ __launch_bounds__(160) void k_wconst(
    const float* __restrict__ sw1, const float* __restrict__ wemb, float* __restrict__ wcst)
{
  int w = blockIdx.x, n = threadIdx.x;
  if (n >= FFD) return;
  float a = 0.f;
  for (int k=0;k<20;k++) a = fmaf(sw1[n*1220 + 1200 + k], wemb[w*20 + k], a);
  wcst[w*FFD + n] = a;
}

// ---------------- K5d: distance-embedding partial ----------------
__global__ __launch_bounds__(160) void k_zd(
    const float* __restrict__ pw1, const float* __restrict__ demb, float* __restrict__ Zd)
{
  int d = blockIdx.x, n = threadIdx.x;
  if (n >= FFD) return;
  float a = 0.f;
  for (int k=0;k<128;k++) a = fmaf(pw1[n*2568 + 2440 + k], demb[d*128 + k], a);
  Zd[d*FFD + n] = a;
}

// ---------------- K3b: span head (z1 combine -> layer2 -> layer3 -> softmax) ----------------
__global__ __launch_bounds__(320) void k_spanhead(
    const float* __restrict__ UV, const float* __restrict__ wcst,
    const float* __restrict__ sb1,
    const float* __restrict__ sw2, const float* __restrict__ sb2,
    const float* __restrict__ sw3, const float* __restrict__ sb3,
    float* __restrict__ sp)
{
  const int b  = blockIdx.y;
  const int s0 = blockIdx.x * 64;
  __shared__ __align__(16) float z1T[160*68];
  __shared__ __align__(16) float z2T[160*68];
  __shared__ __align__(16) float Wt[16*172];
  __shared__ float zf[256];
  __shared__ int sI[64], sJ[64], sW[64];
  const int tid = threadIdx.x;
  if (tid < 64) {
    int s = s0 + tid; int w = 1, i0 = 0;
    if (s < NSP) span_decode(s, w, i0);
    sI[tid] = i0; sJ[tid] = i0 + w - 1; sW[tid] = w;
  }
  __syncthreads();
  for (int idx = tid; idx < 64*160; idx += 320) {
    int p = idx / 160, k = idx - p*160;
    float v = 0.f;
    if (k < FFD && (s0 + p) < NSP) {
      v = UV[(b*LL + sI[p])*300 + k] + UV[(b*LL + sJ[p])*300 + FFD + k]
        + wcst[sW[p]*FFD + k] + sb1[k];
      v = fmaxf(v, 0.f);
    }
    z1T[k*68 + p] = v;
  }
  const int pg = tid / 20, ng = tid - (tid/20)*20;
  float acc[4][8] = {};
  for (int kt = 0; kt < 10; ++kt) {
    __syncthreads();
    for (int idx = tid; idx < 16*160; idx += 320) {
      int n = idx >> 4, kk = idx & 15;
      int k = kt*16 + kk;
      Wt[kk*172 + n] = (n < FFD && k < FFD) ? sw2[n*FFD + k] : 0.f;
    }
    __syncthreads();
    #pragma unroll
    for (int kk = 0; kk < 16; ++kk) {
      float4 a4 = *(const float4*)&z1T[(kt*16+kk)*68 + pg*4];
      float4 w0 = *(const float4*)&Wt[kk*172 + ng*8];
      float4 w1 = *(const float4*)&Wt[kk*172 + ng*8 + 4];
      float a_[4] = {a4.x,a4.y,a4.z,a4.w};
      float w_[8] = {w0.x,w0.y,w0.z,w0.w,w1.x,w1.y,w1.z,w1.w};
      #pragma unroll
      for (int i=0;i<4;i++)
        #pragma unroll
        for (int j=0;j<8;j++)
          acc[i][j] = fmaf(a_[i], w_[j], acc[i][j]);
    }
  }
  __syncthreads();
  #pragma unroll
  for (int j=0;j<8;j++){
    int n = ng*8 + j;
    float bn = (n < FFD) ? sb2[n] : 0.f;
    #pragma unroll
    for (int i=0;i<4;i++){
      float v = (n < FFD) ? fmaxf(acc[i][j] + bn, 0.f) : 0.f;
      z2T[n*68 + pg*4 + i] = v;
    }
  }
  __syncthreads();
  // layer3: 192 active threads (p,c), then 64-thread softmax
  if (tid < 256) {
    int p = tid >> 2, c = tid & 3;
    if (c < 3 && (s0 + p) < NSP) {
      float a = sb3[c];
      for (int k=0;k<FFD;k++) a = fmaf(z2T[k*68 + p], sw3[c*FFD + k], a);
      zf[p*4 + c] = a;
    }
  }
  __syncthreads();
  if (tid < 64 && (s0 + tid) < NSP) {
    float z0 = zf[tid*4], z1 = zf[tid*4+1], z2 = zf[tid*4+2];
    float m = fmaxf(z0, fmaxf(z1, z2));
    float e0 = expf(z0-m), e1 = expf(z1-m), e2 = expf(z2-m);
    float inv = 1.f/(e0+e1+e2);
    int s = s0 + tid;
    sp[(b*NSP + s)*3 + 0] = e0*inv;
    sp[(b*NSP + s)*3 + 1] = e1*inv;
    sp[(b*NSP + s)*3 + 2] = e2*inv;
  }
}

// ---------------- K4: deterministic top-64 (ties -> smaller index, like lax.top_k) ----------------
__global__ __launch_bounds__(64) void k_topk(
    const float* __restrict__ sp, float* __restrict__ outT, float* __restrict__ outO,
    int* __restrict__ idxw)
{
  const int cls = blockIdx.x >> 3;   // 0: aspect(col1), 1: opinion(col2)
  const int b   = blockIdx.x & 7;
  const int lane = threadIdx.x;
  uint64_t key[10];
  #pragma unroll
  for (int q=0;q<10;q++){
    int s = lane + q*64;
    uint32_t bits = 0u;
    if (s < NSP) bits = __float_as_uint(sp[(b*NSP + s)*3 + 1 + cls]);
    key[q] = ((uint64_t)bits << 32) | (uint32_t)(1023 - s);
  }
  float* dst = cls ? outO : outT;
  for (int r = 0; r < NZK; ++r) {
    uint64_t best = key[0];
    #pragma unroll
    for (int q=1;q<10;q++) best = key[q] > best ? key[q] : best;
    #pragma unroll
    for (int off = 32; off > 0; off >>= 1) {
      uint64_t o = shfl_xor_u64(best, off);
      best = o > best ? o : best;
    }
    int sWin = 1023 - (int)(best & 0xFFFFFFFFu);
    if ((sWin & 63) == lane) {
      int qw = sWin >> 6;
      #pragma unroll
      for (int q=0;q<10;q++) if (q == qw) key[q] = 0;
    }
    if (lane == 0) {
      dst[b*NZK + r] = (float)sWin;
      idxw[cls*512 + b*NZK + r] = sWin;
    }
  }
}

// ---------------- K5a: Zt/Zo partial pair projections over selected spans ----------------
// slot = cls*512 + b*64 + rank ; ZTO[slot][150] = pw1[:, cls*1220 : +1220] @ span_vec(slot)
__global__ __launch_bounds__(320) void k_zto(
    const float* __restrict__ out, const float* __restrict__ wemb,
    const float* __restrict__ pw1, const int* __restrict__ idxw,
    float* __restrict__ ZTO)
{
  const int wg = blockIdx.x;
  const int cls = wg >> 5;
  const int rem = wg & 31;
  const int b = rem >> 2;
  const int i0 = (rem & 3) * 16;
  __shared__ float As[16*20];
  __shared__ __align__(16) float Wt[16*172];
  __shared__ int sI[16], sJ[16], sW[16];
  const int tid = threadIdx.x;
  if (tid < 16) {
    int S = idxw[cls*512 + b*64 + i0 + tid];
    int w, i_; span_decode(S, w, i_);
    sI[tid] = i_; sJ[tid] = i_ + w - 1; sW[tid] = w;
  }
  const int pg = tid / 20, ng = tid - (tid/20)*20;
  float acc[8] = {};
  __syncthreads();
  for (int k0 = 0; k0 < 1232; k0 += 16) {
    if (tid < 256) {
      int p = tid >> 4, kk = tid & 15;
      int k = k0 + kk;
      float v = 0.f;
      if      (k < 600)  v = out[(b*LL + sI[p])*600 + k];
      else if (k < 1200) v = out[(b*LL + sJ[p])*600 + (k - 600)];
      else if (k < 1220) v = wemb[sW[p]*20 + (k - 1200)];
      As[kk*20 + p] = v;
    }
    for (int idx = tid; idx < 16*160; idx += 320) {
      int n = idx >> 4, kk = idx & 15;
      int k = k0 + kk;
      Wt[kk*172 + n] = (n < FFD && k < 1220) ? pw1[n*2568 + cls*1220 + k] : 0.f;
    }
    __syncthreads();
    #pragma unroll
    for (int kk=0;kk<16;kk++){
      float a = As[kk*20 + pg];
      float4 w0 = *(const float4*)&Wt[kk*172 + ng*8];
      float4 w1 = *(const float4*)&Wt[kk*172 + ng*8 + 4];
      acc[0] = fmaf(a, w0.x, acc[0]);
      acc[1] = fmaf(a, w0.y, acc[1]);
      acc[2] = fmaf(a, w0.z, acc[2]);
      acc[3] = fmaf(a, w0.w, acc[3]);
      acc[4] = fmaf(a, w1.x, acc[4]);
      acc[5] = fmaf(a, w1.y, acc[5]);
      acc[6] = fmaf(a, w1.z, acc[6]);
      acc[7] = fmaf(a, w1.w, acc[7]);
    }
    __syncthreads();
  }
  #pragma unroll
  for (int j=0;j<8;j++){
    int n = ng*8 + j;
    if (n < FFD) ZTO[(cls*512 + b*64 + i0 + pg)*FFD + n] = acc[j];
  }
}

// ---------------- K5b: pair head ----------------
__global__ __launch_bounds__(320) void k_pairhead(
    const float* __restrict__ ZTO, const float* __restrict__ Zd,
    const float* __restrict__ pb1,
    const float* __restrict__ pw2, const float* __restrict__ pb2,
    const float* __restrict__ pw3, const float* __restrict__ pb3,
    const int* __restrict__ idxw,
    float* __restrict__ cp)
{
  const int b  = blockIdx.y;
  const int ti = blockIdx.x;
  __shared__ __align__(16) float z1T[160*68];
  __shared__ __align__(16) float z2T[160*68];
  __shared__ __align__(16) float Wt[16*172];
  __shared__ float zf[256];
  __shared__ int oDist[64];
  const int tid = threadIdx.x;
  const int tS = idxw[b*64 + ti];
  int wT, iT; span_decode(tS, wT, iT);
  const int aT = iT, bT = iT + wT - 1;
  if (tid < 64) {
    int oS = idxw[512 + b*64 + tid];
    int wO, iO; span_decode(oS, wO, iO);
    int d1 = bT - iO;            if (d1 < 0) d1 = -d1;
    int d2 = aT - (iO + wO - 1); if (d2 < 0) d2 = -d2;
    oDist[tid] = d1 < d2 ? d1 : d2;
  }
  __syncthreads();
  const float* ZtRow = ZTO + (b*64 + ti)*FFD;
  for (int idx = tid; idx < 64*160; idx += 320) {
    int p = idx / 160, k = idx - p*160;
    float v = 0.f;
    if (k < FFD) {
      v = ZtRow[k] + ZTO[(512 + b*64 + p)*FFD + k] + Zd[oDist[p]*FFD + k] + pb1[k];
      v = fmaxf(v, 0.f);
    }
    z1T[k*68 + p] = v;
  }
  const int pg = tid / 20, ng = tid - (tid/20)*20;
  float acc[4][8] = {};
  for (int kt = 0; kt < 10; ++kt) {
    __syncthreads();
    for (int idx = tid; idx < 16*160; idx += 320) {
      int n = idx >> 4, kk = idx & 15;
      int k = kt*16 + kk;
      Wt[kk*172 + n] = (n < FFD && k < FFD) ? pw2[n*FFD + k] : 0.f;
    }
    __syncthreads();
    #pragma unroll
    for (int kk = 0; kk < 16; ++kk) {
      float4 a4 = *(const float4*)&z1T[(kt*16+kk)*68 + pg*4];
      float4 w0 = *(const float4*)&Wt[kk*172 + ng*8];
      float4 w1 = *(const float4*)&Wt[kk*172 + ng*8 + 4];
      float a_[4] = {a4.x,a4.y,a4.z,a4.w};
      float w_[8] = {w0.x,w0.y,w0.z,w0.w,w1.x,w1.y,w1.z,w1.w};
      #pragma unroll
      for (int i=0;i<4;i++)
        #pragma unroll
        for (int j=0;j<8;j++)
          acc[i][j] = fmaf(a_[i], w_[j], acc[i][j]);
    }
  }
  __syncthreads();
  #pragma unroll
  for (int j=0;j<8;j++){
    int n = ng*8 + j;
    float bn = (n < FFD) ? pb2[n] : 0.f;
    #pragma unroll
    for (int i=0;i<4;i++){
      float v = (n < FFD) ? fmaxf(acc[i][j] + bn, 0.f) : 0.f;
      z2T[n*68 + pg*4 + i] = v;
    }
  }
  __syncthreads();
  // layer3: 256 threads (p,c), then 64-thread softmax
  if (tid < 256) {
    int p = tid >> 2, c = tid & 3;
    float a = pb3[c];
    for (int k=0;k<FFD;k++) a = fmaf(z2T[k*68 + p], pw3[c*FFD + k], a);
    zf[tid] = a;
  }
  __syncthreads();
  if (tid < 64) {
    float z0 = zf[tid*4], z1 = zf[tid*4+1], z2 = zf[tid*4+2], z3 = zf[tid*4+3];
    float m = fmaxf(fmaxf(z0,z1), fmaxf(z2,z3));
    float e0 = expf(z0-m), e1 = expf(z1-m), e2 = expf(z2-m), e3 = expf(z3-m);
    float inv = 1.f/(e0+e1+e2+e3);
    float4 o4 = make_float4(e0*inv, e1*inv, e2*inv, e3*inv);
    *(float4*)&cp[(size_t)((b*4096 + ti*64 + tid))*4] = o4;
  }
}

// ---------------- launch ----------------
extern "C" void kernel_launch(void* const* d_in, const int* in_sizes, int n_in,
                              void* d_out, int out_size, void* d_ws, size_t ws_size,
                              hipStream_t stream) {
  const float* x    = (const float*)d_in[0];
  const float* WihF = (const float*)d_in[1];
  const float* WhhF = (const float*)d_in[2];
  const float* bihF = (const float*)d_in[3];
  const float* bhhF = (const float*)d_in[4];
  const float* WihB = (const float*)d_in[5];
  const float* WhhB = (const float*)d_in[6];
  const float* bihB = (const float*)d_in[7];
  const float* bhhB = (const float*)d_in[8];
  const float* wemb = (const float*)d_in[9];
  const float* demb = (const float*)d_in[10];
  const float* sw1  = (const float*)d_in[11];
  const float* sb1  = (const float*)d_in[12];
  const float* sw2  = (const float*)d_in[13];
  const float* sb2  = (const float*)d_in[14];
  const float* sw3  = (const float*)d_in[15];
  const float* sb3  = (const float*)d_in[16];
  const float* pw1  = (const float*)d_in[17];
  const float* pb1  = (const float*)d_in[18];
  const float* pw2  = (const float*)d_in[19];
  const float* pb2  = (const float*)d_in[20];
  const float* pw3  = (const float*)d_in[21];
  const float* pb3  = (const float*)d_in[22];

  uint8_t* wsb = (uint8_t*)d_ws;
  unsigned int* flags = (unsigned int*)wsb;        // 60 slots, 128B apart (8 KB)
  float* hbuf = (float*)(wsb + 8192);              // [2][2][8][320] = 10240 f
  float* xg   = (float*)(wsb + 131072);            // [2][128][1200][8] = 2457600 f
  float* outh = xg   + 2457600;                    // [8][128][600]     = 614400 f
  float* UV   = outh + 614400;                     // [1024][300]       = 307200 f
  float* wcst = UV   + 307200;                     // [6][150]          = 900 f
  float* Zd   = wcst + 900;                        // [256][150]        = 38400 f
  float* ZTO  = Zd   + 38400;                      // [1024][150]       = 153600 f
  int*  idxw  = (int*)(ZTO + 153600);              // [2][8][64]        = 1024 i

  float* o   = (float*)d_out;
  float* spO = o;              // [8][630][3]  = 15120
  float* cpO = o + 15120;      // [8][4096][4] = 131072
  float* tO  = o + 146192;     // [8][64]
  float* oO  = o + 146704;     // [8][64]

  k_xg      <<<dim3(19,16,2), 256, 0, stream>>>(x, WihF, bihF, bhhF, WihB, bihB, bhhB, xg, flags);
  k_lstm    <<<dim3(2*WG_PER_DIR), 320, 0, stream>>>(WhhF, WhhB, xg, hbuf, outh, flags);
  k_uv      <<<dim3(32,1,2), 320, 0, stream>>>(outh, sw1, UV);
  k_wconst  <<<dim3(6),   160, 0, stream>>>(sw1, wemb, wcst);
  k_zd      <<<dim3(256), 160, 0, stream>>>(pw1, demb, Zd);
  k_spanhead<<<dim3(10,8), 320, 0, stream>>>(UV, wcst, sb1, sw2, sb2, sw3, sb3, spO);
  k_topk    <<<dim3(16),  64, 0, stream>>>(spO, tO, oO, idxw);
  k_zto     <<<dim3(64),  320, 0, stream>>>(outh, wemb, pw1, idxw, ZTO);
  k_pairhead<<<dim3(64,8), 320, 0, stream>>>(ZTO, Zd, pb1, pw2, pb2, pw3, pb3, idxw, cpO);
}

// Round 3
// 1370.294 us; speedup vs baseline: 1.2952x; 1.0896x over previous
//
#include <hip/hip_runtime.h>
#include <stdint.h>
#include <stddef.h>

// ---------------- problem constants ----------------
#define BB   8
#define LL   128
#define DD   768
#define HH   300
#define G4   1200     // 4*H
#define NSP  630      // number of spans
#define FFD  150
#define NZK  64       // top-k

// LSTM persistent-kernel geometry: 60 WGs/dir, 5 h-rows/WG, 16 k-segments
#define WPD  60
#define JC   5        // h indices per wg
#define NROW 20       // gate rows per wg (4*JC)

__device__ __forceinline__ float sigm(float x){ return 1.0f/(1.0f+expf(-x)); }

__device__ __forceinline__ void span_decode(int s, int& w, int& i){
  if      (s < 128){ w=1; i=s; }
  else if (s < 255){ w=2; i=s-128; }
  else if (s < 381){ w=3; i=s-255; }
  else if (s < 506){ w=4; i=s-381; }
  else             { w=5; i=s-506; }
}

__device__ __forceinline__ uint64_t shfl_xor_u64(uint64_t v, int m){
  uint32_t lo = (uint32_t)v, hi = (uint32_t)(v >> 32);
  lo = (uint32_t)__shfl_xor((int)lo, m, 64);
  hi = (uint32_t)__shfl_xor((int)hi, m, 64);
  return ((uint64_t)hi << 32) | lo;
}

// ---------------- K1: xg = Wih @ x + bih + bhh  (both dirs) ----------------
// xg layout: [dir][t][1200][8].  Block (0,0,0) also clears the hexch tags
// (sc1 stores -> MALL) so k_lstm's coherent polls can never see stale tags.
__global__ __launch_bounds__(256) void k_xg(
    const float* __restrict__ x,
    const float* __restrict__ WihF, const float* __restrict__ bihF, const float* __restrict__ bhhF,
    const float* __restrict__ WihB, const float* __restrict__ bihB, const float* __restrict__ bhhB,
    float* __restrict__ xg, unsigned long long* __restrict__ hexch)
{
  if (blockIdx.x==0 && blockIdx.y==0 && blockIdx.z==0) {
    for (int i = threadIdx.x; i < 2*8*320; i += 256)
      __hip_atomic_store(&hexch[i], 0ull, __ATOMIC_RELAXED, __HIP_MEMORY_SCOPE_AGENT);
  }
  const int dir = blockIdx.z;
  const float* Wih = dir ? WihB : WihF;
  const float* bi  = dir ? bihB : bihF;
  const float* bh  = dir ? bhhB : bhhF;
  const int r0 = blockIdx.x * 64;
  const int n0 = blockIdx.y * 64;   // n = t*8 + b
  __shared__ __align__(16) float As[16*68];
  __shared__ __align__(16) float Bs[16*68];
  const int tid = threadIdx.x;
  const int rl = tid >> 2, kq = tid & 3;
  const int tx = tid & 15, ty = tid >> 4;
  float acc[4][4] = {};
  for (int k0 = 0; k0 < DD; k0 += 16) {
    float4 a4 = make_float4(0.f,0.f,0.f,0.f);
    int ra = r0 + rl;
    if (ra < G4) a4 = *(const float4*)&Wih[ra*DD + k0 + kq*4];
    As[(kq*4+0)*68 + rl] = a4.x;
    As[(kq*4+1)*68 + rl] = a4.y;
    As[(kq*4+2)*68 + rl] = a4.z;
    As[(kq*4+3)*68 + rl] = a4.w;
    int n = n0 + rl; int tt = n >> 3, bb = n & 7;
    float4 b4 = *(const float4*)&x[(bb*LL + tt)*DD + k0 + kq*4];
    Bs[(kq*4+0)*68 + rl] = b4.x;
    Bs[(kq*4+1)*68 + rl] = b4.y;
    Bs[(kq*4+2)*68 + rl] = b4.z;
    Bs[(kq*4+3)*68 + rl] = b4.w;
    __syncthreads();
    #pragma unroll
    for (int kk = 0; kk < 16; ++kk) {
      float4 av = *(const float4*)&As[kk*68 + tx*4];
      float4 bv = *(const float4*)&Bs[kk*68 + ty*4];
      float a_[4] = {av.x,av.y,av.z,av.w};
      float b_[4] = {bv.x,bv.y,bv.z,bv.w};
      #pragma unroll
      for (int i=0;i<4;i++)
        #pragma unroll
        for (int j=0;j<4;j++)
          acc[i][j] = fmaf(a_[i], b_[j], acc[i][j]);
    }
    __syncthreads();
  }
  #pragma unroll
  for (int i=0;i<4;i++){
    int r = r0 + tx*4 + i;
    if (r >= G4) continue;
    float bias = bi[r] + bh[r];
    #pragma unroll
    for (int j=0;j<4;j++){
      int n = n0 + ty*4 + j; int tt = n>>3, bb = n&7;
      xg[((dir*LL + tt)*G4 + r)*8 + bb] = acc[i][j] + bias;
    }
  }
}

// ---------------- K2: persistent bidirectional LSTM ----------------
// 120 wg (60/dir); each owns JC=5 h-rows (20 gate rows), Whh slice in regs
// (5 float4/thread). h exchange: ONE tagged u64 per value,
// relaxed agent-scope (sc1) store, fire-and-forget; consumers poll until
// tag==t. No flags, no vmcnt(0), no fences. Segment reduction: in-wave
// butterfly reduce-scatter over 16 lanes. 2 barriers/step.
// hexch: [dir][8][320] u64; tag 0 preset by k_xg; harness 0xAA poison is
// also a non-matching tag.
__global__ __launch_bounds__(320) void k_lstm(
    const float* __restrict__ WhhF, const float* __restrict__ WhhB,
    const float* __restrict__ xg,
    unsigned long long* __restrict__ hexch,
    float* __restrict__ out)            // [b][t][600]
{
  const int wg  = blockIdx.x;
  const int dir = wg / WPD;
  const int wid = wg - dir*WPD;
  const int j0  = wid * JC;
  const float* Whh = dir ? WhhB : WhhF;
  unsigned long long* hex = hexch + (size_t)dir*2560;

  __shared__ __align__(16) float hls[8*320];
  __shared__ float gls[NROW*8];
  __shared__ float cst[JC*8];

  const int tid = threadIdx.x;
  const int r = tid >> 4;           // 0..19 gate-row slot
  const int s = tid & 15;           // k-segment 0..15 (20 floats each)
  const int gate = r / JC, jj = r - gate*JC;
  const int Rabs = gate*HH + j0 + jj;
  const int bb = s & 7;

  // register-resident Whh slice: 20 floats (5 float4) per thread
  float4 w4[5];
  #pragma unroll
  for (int q=0;q<5;q++){
    int k = s*20 + q*4;
    if (k + 3 < HH) w4[q] = *(const float4*)&Whh[Rabs*HH + k];
    else            w4[q] = make_float4(0.f,0.f,0.f,0.f);
  }
  if (tid < JC*8) cst[tid] = 0.f;
  if (tid >= 300) {                       // LDS pads stay zero forever
    #pragma unroll
    for (int b=0;b<8;b++) hls[b*320 + tid] = 0.f;
  }

  // xg prefetch for t=0
  float xg_c = xg[((size_t)(dir*LL + (dir ? LL-1 : 0))*G4 + Rabs)*8 + bb];

  for (int t = 0; t < LL; ++t) {
    const int tOrig = dir ? (LL-1 - t) : t;
    // prefetch next step's xg (overlaps the poll latency)
    float xg_n = 0.f;
    if (t+1 < LL) {
      int tO2 = dir ? (LL-2 - t) : (t+1);
      xg_n = xg[((size_t)(dir*LL + tO2)*G4 + Rabs)*8 + bb];
    }
    // stage A: acquire h_prev
    if (t == 0) {
      if (tid < 300) {
        #pragma unroll
        for (int b=0;b<8;b++) hls[b*320 + tid] = 0.f;
      }
    } else if (tid < 300) {
      unsigned got = 0; float v[8];
      const unsigned want = (unsigned)t;
      while (got != 0xFFu) {
        #pragma unroll
        for (int b=0;b<8;b++) if (!(got & (1u<<b))) {
          unsigned long long u =
            __hip_atomic_load(&hex[b*320 + tid], __ATOMIC_RELAXED, __HIP_MEMORY_SCOPE_AGENT);
          if ((unsigned)(u >> 32) == want) {
            v[b] = __uint_as_float((unsigned)u);
            got |= 1u<<b;
          }
        }
        if (got != 0xFFu) __builtin_amdgcn_s_sleep(1);
      }
      #pragma unroll
      for (int b=0;b<8;b++) hls[b*320 + tid] = v[b];
    }
    __syncthreads();
    // stage B: partial dot products (20 floats per thread per batch)
    float p[8];
    {
      const float4* h4 = (const float4*)hls;
      #pragma unroll
      for (int b=0;b<8;b++){
        const float4* hb = h4 + b*80 + s*5;
        float ax=0.f, ay=0.f, az=0.f, aw=0.f;
        #pragma unroll
        for (int q=0;q<5;q++){
          float4 hv = hb[q];
          ax = fmaf(w4[q].x, hv.x, ax);
          ay = fmaf(w4[q].y, hv.y, ay);
          az = fmaf(w4[q].z, hv.z, az);
          aw = fmaf(w4[q].w, hv.w, aw);
        }
        p[b] = (ax+ay)+(az+aw);
      }
    }
    // reduce over the 16 s-lanes: full add over bit3, reduce-scatter bits 2..0
    #pragma unroll
    for (int b=0;b<8;b++) p[b] += __shfl_xor(p[b], 8, 64);
    float q4[4];
    #pragma unroll
    for (int b=0;b<4;b++){
      float mine = (s&4) ? p[b+4] : p[b];
      float oth  = (s&4) ? p[b]   : p[b+4];
      q4[b] = mine + __shfl_xor(oth, 4, 64);
    }
    float q2[2];
    #pragma unroll
    for (int b=0;b<2;b++){
      float mine = (s&2) ? q4[b+2] : q4[b];
      float oth  = (s&2) ? q4[b]   : q4[b+2];
      q2[b] = mine + __shfl_xor(oth, 2, 64);
    }
    {
      float mine = (s&1) ? q2[1] : q2[0];
      float oth  = (s&1) ? q2[0] : q2[1];
      float g = mine + __shfl_xor(oth, 1, 64);
      if (s < 8) gls[r*8 + s] = g + xg_c;   // g for batch b = s
    }
    __syncthreads();
    // stage D: cell update (40 threads: j x b); tagged u64 publish
    if (tid < JC*8) {
      int j = tid >> 3, b = tid & 7;
      float ig = sigm(gls[(       j)*8 + b]);
      float fg = sigm(gls[(JC   + j)*8 + b]);
      float gg = tanhf(gls[(2*JC + j)*8 + b]);
      float og = sigm(gls[(3*JC + j)*8 + b]);
      float c  = fg * cst[tid] + ig * gg;
      cst[tid] = c;
      float h  = og * tanhf(c);
      out[((size_t)(b*LL + tOrig))*600 + dir*HH + j0 + j] = h;
      if (t+1 < LL) {
        unsigned long long pkt =
          ((unsigned long long)(unsigned)(t+1) << 32) |
          (unsigned long long)__float_as_uint(h);
        __hip_atomic_store(&hex[b*320 + j0 + j], pkt,
                           __ATOMIC_RELAXED, __HIP_MEMORY_SCOPE_AGENT);
      }
    }
    // no barrier here: non-D threads run ahead into the next poll (overlap);
    // gls(t+1) writes are fenced from stage-D reads by barrier(1) of t+1.
    xg_c = xg_n;
  }
}

// ---------------- K3a: U/V partial span projections ----------------
// UV[row][half*150+n] = sum_k sw1[n][half*600+k] * out[row][k],  row = b*128+l
__global__ __launch_bounds__(320) void k_uv(
    const float* __restrict__ out, const float* __restrict__ sw1, float* __restrict__ UV)
{
  const int half = blockIdx.z;
  const int row0 = blockIdx.x * 32;
  __shared__ float As[16*36];
  __shared__ __align__(16) float Wt[16*172];
  const int tid = threadIdx.x;
  const int pg = tid / 20, ng = tid - (tid/20)*20;
  float acc[2][8] = {};
  for (int k0 = 0; k0 < 600; k0 += 16) {
    for (int idx = tid; idx < 512; idx += 320) {
      int p = idx >> 4, kk = idx & 15;
      int k = k0 + kk;
      As[kk*36 + p] = (k < 600) ? out[(row0 + p)*600 + k] : 0.f;
    }
    for (int idx = tid; idx < 16*160; idx += 320) {
      int n = idx >> 4, kk = idx & 15;
      int k = k0 + kk;
      Wt[kk*172 + n] = (n < FFD && k < 600) ? sw1[n*1220 + half*600 + k] : 0.f;
    }
    __syncthreads();
    #pragma unroll
    for (int kk=0;kk<16;kk++){
      float2 a2 = *(const float2*)&As[kk*36 + pg*2];
      float4 w0 = *(const float4*)&Wt[kk*172 + ng*8];
      float4 w1 = *(const float4*)&Wt[kk*172 + ng*8 + 4];
      float a_[2] = {a2.x, a2.y};
      float w_[8] = {w0.x,w0.y,w0.z,w0.w,w1.x,w1.y,w1.z,w1.w};
      #pragma unroll
      for (int i=0;i<2;i++)
        #pragma unroll
        for (int j=0;j<8;j++)
          acc[i][j] = fmaf(a_[i], w_[j], acc[i][j]);
    }
    __syncthreads();
  }
  #pragma unroll
  for (int i=0;i<2;i++){
    int row = row0 + pg*2 + i;
    #pragma unroll
    for (int j=0;j<8;j++){
      int n = ng*8 + j;
      if (n < FFD) UV[row*300 + half*FFD + n] = acc[i][j];
    }
  }
}

// ---------------- K3w+K5d merged: width-emb & dist-emb partials ----------------
__global__ __launch_bounds__(160) void k_const(
    const float* __restrict__ sw1, const float* __restrict__ wemb, float* __restrict__ wcst,
    const float* __restrict__ pw1, const float* __restrict__ demb, float* __restrict__ Zd)
{
  int n = threadIdx.x;
  if (n >= FFD) return;
  if (blockIdx.x < 6) {
    int w = blockIdx.x;
    float a = 0.f;
    for (int k=0;k<20;k++) a = fmaf(sw1[n*1220 + 1200 + k], wemb[w*20 + k], a);
    wcst[w*FFD + n] = a;
  } else {
    int d = blockIdx.x - 6;
    float a = 0.f;
    for (int k=0;k<128;k++) a = fmaf(pw1[n*2568 + 2440 + k], demb[d*128 + k], a);
    Zd[d*FFD + n] = a;
  }
}

// ---------------- K3b: span head (z1 combine -> layer2 -> layer3 -> softmax) ----------------
__global__ __launch_bounds__(320) void k_spanhead(
    const float* __restrict__ UV, const float* __restrict__ wcst,
    const float* __restrict__ sb1,
    const float* __restrict__ sw2, const float* __restrict__ sb2,
    const float* __restrict__ sw3, const float* __restrict__ sb3,
    float* __restrict__ sp)
{
  const int b  = blockIdx.y;
  const int s0 = blockIdx.x * 64;
  __shared__ __align__(16) float z1T[160*68];
  __shared__ __align__(16) float z2T[160*68];
  __shared__ __align__(16) float Wt[16*172];
  __shared__ float zf[256];
  __shared__ int sI[64], sJ[64], sW[64];
  const int tid = threadIdx.x;
  if (tid < 64) {
    int s = s0 + tid; int w = 1, i0 = 0;
    if (s < NSP) span_decode(s, w, i0);
    sI[tid] = i0; sJ[tid] = i0 + w - 1; sW[tid] = w;
  }
  __syncthreads();
  for (int idx = tid; idx < 64*160; idx += 320) {
    int p = idx / 160, k = idx - p*160;
    float v = 0.f;
    if (k < FFD && (s0 + p) < NSP) {
      v = UV[(b*LL + sI[p])*300 + k] + UV[(b*LL + sJ[p])*300 + FFD + k]
        + wcst[sW[p]*FFD + k] + sb1[k];
      v = fmaxf(v, 0.f);
    }
    z1T[k*68 + p] = v;
  }
  const int pg = tid / 20, ng = tid - (tid/20)*20;
  float acc[4][8] = {};
  for (int kt = 0; kt < 10; ++kt) {
    __syncthreads();
    for (int idx = tid; idx < 16*160; idx += 320) {
      int n = idx >> 4, kk = idx & 15;
      int k = kt*16 + kk;
      Wt[kk*172 + n] = (n < FFD && k < FFD) ? sw2[n*FFD + k] : 0.f;
    }
    __syncthreads();
    #pragma unroll
    for (int kk = 0; kk < 16; ++kk) {
      float4 a4 = *(const float4*)&z1T[(kt*16+kk)*68 + pg*4];
      float4 w0 = *(const float4*)&Wt[kk*172 + ng*8];
      float4 w1 = *(const float4*)&Wt[kk*172 + ng*8 + 4];
      float a_[4] = {a4.x,a4.y,a4.z,a4.w};
      float w_[8] = {w0.x,w0.y,w0.z,w0.w,w1.x,w1.y,w1.z,w1.w};
      #pragma unroll
      for (int i=0;i<4;i++)
        #pragma unroll
        for (int j=0;j<8;j++)
          acc[i][j] = fmaf(a_[i], w_[j], acc[i][j]);
    }
  }
  __syncthreads();
  #pragma unroll
  for (int j=0;j<8;j++){
    int n = ng*8 + j;
    float bn = (n < FFD) ? sb2[n] : 0.f;
    #pragma unroll
    for (int i=0;i<4;i++){
      float v = (n < FFD) ? fmaxf(acc[i][j] + bn, 0.f) : 0.f;
      z2T[n*68 + pg*4 + i] = v;
    }
  }
  __syncthreads();
  if (tid < 256) {
    int p = tid >> 2, c = tid & 3;
    if (c < 3 && (s0 + p) < NSP) {
      float a = sb3[c];
      for (int k=0;k<FFD;k++) a = fmaf(z2T[k*68 + p], sw3[c*FFD + k], a);
      zf[p*4 + c] = a;
    }
  }
  __syncthreads();
  if (tid < 64 && (s0 + tid) < NSP) {
    float z0 = zf[tid*4], z1 = zf[tid*4+1], z2 = zf[tid*4+2];
    float m = fmaxf(z0, fmaxf(z1, z2));
    float e0 = expf(z0-m), e1 = expf(z1-m), e2 = expf(z2-m);
    float inv = 1.f/(e0+e1+e2);
    int s = s0 + tid;
    sp[(b*NSP + s)*3 + 0] = e0*inv;
    sp[(b*NSP + s)*3 + 1] = e1*inv;
    sp[(b*NSP + s)*3 + 2] = e2*inv;
  }
}

// ---------------- K4: deterministic top-64 (ties -> smaller index) ----------------
__global__ __launch_bounds__(64) void k_topk(
    const float* __restrict__ sp, float* __restrict__ outT, float* __restrict__ outO,
    int* __restrict__ idxw)
{
  const int cls = blockIdx.x >> 3;   // 0: aspect(col1), 1: opinion(col2)
  const int b   = blockIdx.x & 7;
  const int lane = threadIdx.x;
  uint64_t key[10];
  #pragma unroll
  for (int q=0;q<10;q++){
    int s = lane + q*64;
    uint32_t bits = 0u;
    if (s < NSP) bits = __float_as_uint(sp[(b*NSP + s)*3 + 1 + cls]);
    key[q] = ((uint64_t)bits << 32) | (uint32_t)(1023 - s);
  }
  float* dst = cls ? outO : outT;
  for (int r = 0; r < NZK; ++r) {
    uint64_t best = key[0];
    #pragma unroll
    for (int q=1;q<10;q++) best = key[q] > best ? key[q] : best;
    #pragma unroll
    for (int off = 32; off > 0; off >>= 1) {
      uint64_t o = shfl_xor_u64(best, off);
      best = o > best ? o : best;
    }
    int sWin = 1023 - (int)(best & 0xFFFFFFFFu);
    if ((sWin & 63) == lane) {
      int qw = sWin >> 6;
      #pragma unroll
      for (int q=0;q<10;q++) if (q == qw) key[q] = 0;
    }
    if (lane == 0) {
      dst[b*NZK + r] = (float)sWin;
      idxw[cls*512 + b*NZK + r] = sWin;
    }
  }
}

// ---------------- K5a: Zt/Zo partial pair projections over selected spans ----------------
__global__ __launch_bounds__(320) void k_zto(
    const float* __restrict__ out, const float* __restrict__ wemb,
    const float* __restrict__ pw1, const int* __restrict__ idxw,
    float* __restrict__ ZTO)
{
  const int wg = blockIdx.x;
  const int cls = wg >> 5;
  const int rem = wg & 31;
  const int b = rem >> 2;
  const int i0 = (rem & 3) * 16;
  __shared__ float As[16*20];
  __shared__ __align__(16) float Wt[16*172];
  __shared__ int sI[16], sJ[16], sW[16];
  const int tid = threadIdx.x;
  if (tid < 16) {
    int S = idxw[cls*512 + b*64 + i0 + tid];
    int w, i_; span_decode(S, w, i_);
    sI[tid] = i_; sJ[tid] = i_ + w - 1; sW[tid] = w;
  }
  const int pg = tid / 20, ng = tid - (tid/20)*20;
  float acc[8] = {};
  __syncthreads();
  for (int k0 = 0; k0 < 1232; k0 += 16) {
    if (tid < 256) {
      int p = tid >> 4, kk = tid & 15;
      int k = k0 + kk;
      float v = 0.f;
      if      (k < 600)  v = out[(b*LL + sI[p])*600 + k];
      else if (k < 1200) v = out[(b*LL + sJ[p])*600 + (k - 600)];
      else if (k < 1220) v = wemb[sW[p]*20 + (k - 1200)];
      As[kk*20 + p] = v;
    }
    for (int idx = tid; idx < 16*160; idx += 320) {
      int n = idx >> 4, kk = idx & 15;
      int k = k0 + kk;
      Wt[kk*172 + n] = (n < FFD && k < 1220) ? pw1[n*2568 + cls*1220 + k] : 0.f;
    }
    __syncthreads();
    #pragma unroll
    for (int kk=0;kk<16;kk++){
      float a = As[kk*20 + pg];
      float4 w0 = *(const float4*)&Wt[kk*172 + ng*8];
      float4 w1 = *(const float4*)&Wt[kk*172 + ng*8 + 4];
      acc[0] = fmaf(a, w0.x, acc[0]);
      acc[1] = fmaf(a, w0.y, acc[1]);
      acc[2] = fmaf(a, w0.z, acc[2]);
      acc[3] = fmaf(a, w0.w, acc[3]);
      acc[4] = fmaf(a, w1.x, acc[4]);
      acc[5] = fmaf(a, w1.y, acc[5]);
      acc[6] = fmaf(a, w1.z, acc[6]);
      acc[7] = fmaf(a, w1.w, acc[7]);
    }
    __syncthreads();
  }
  #pragma unroll
  for (int j=0;j<8;j++){
    int n = ng*8 + j;
    if (n < FFD) ZTO[(cls*512 + b*64 + i0 + pg)*FFD + n] = acc[j];
  }
}

// ---------------- K5b: pair head ----------------
__global__ __launch_bounds__(320) void k_pairhead(
    const float* __restrict__ ZTO, const float* __restrict__ Zd,
    const float* __restrict__ pb1,
    const float* __restrict__ pw2, const float* __restrict__ pb2,
    const float* __restrict__ pw3, const float* __restrict__ pb3,
    const int* __restrict__ idxw,
    float* __restrict__ cp)
{
  const int b  = blockIdx.y;
  const int ti = blockIdx.x;
  __shared__ __align__(16) float z1T[160*68];
  __shared__ __align__(16) float z2T[160*68];
  __shared__ __align__(16) float Wt[16*172];
  __shared__ float zf[256];
  __shared__ int oDist[64];
  const int tid = threadIdx.x;
  const int tS = idxw[b*64 + ti];
  int wT, iT; span_decode(tS, wT, iT);
  const int aT = iT, bT = iT + wT - 1;
  if (tid < 64) {
    int oS = idxw[512 + b*64 + tid];
    int wO, iO; span_decode(oS, wO, iO);
    int d1 = bT - iO;            if (d1 < 0) d1 = -d1;
    int d2 = aT - (iO + wO - 1); if (d2 < 0) d2 = -d2;
    oDist[tid] = d1 < d2 ? d1 : d2;
  }
  __syncthreads();
  const float* ZtRow = ZTO + (b*64 + ti)*FFD;
  for (int idx = tid; idx < 64*160; idx += 320) {
    int p = idx / 160, k = idx - p*160;
    float v = 0.f;
    if (k < FFD) {
      v = ZtRow[k] + ZTO[(512 + b*64 + p)*FFD + k] + Zd[oDist[p]*FFD + k] + pb1[k];
      v = fmaxf(v, 0.f);
    }
    z1T[k*68 + p] = v;
  }
  const int pg = tid / 20, ng = tid - (tid/20)*20;
  float acc[4][8] = {};
  for (int kt = 0; kt < 10; ++kt) {
    __syncthreads();
    for (int idx = tid; idx < 16*160; idx += 320) {
      int n = idx >> 4, kk = idx & 15;
      int k = kt*16 + kk;
      Wt[kk*172 + n] = (n < FFD && k < FFD) ? pw2[n*FFD + k] : 0.f;
    }
    __syncthreads();
    #pragma unroll
    for (int kk = 0; kk < 16; ++kk) {
      float4 a4 = *(const float4*)&z1T[(kt*16+kk)*68 + pg*4];
      float4 w0 = *(const float4*)&Wt[kk*172 + ng*8];
      float4 w1 = *(const float4*)&Wt[kk*172 + ng*8 + 4];
      float a_[4] = {a4.x,a4.y,a4.z,a4.w};
      float w_[8] = {w0.x,w0.y,w0.z,w0.w,w1.x,w1.y,w1.z,w1.w};
      #pragma unroll
      for (int i=0;i<4;i++)
        #pragma unroll
        for (int j=0;j<8;j++)
          acc[i][j] = fmaf(a_[i], w_[j], acc[i][j]);
    }
  }
  __syncthreads();
  #pragma unroll
  for (int j=0;j<8;j++){
    int n = ng*8 + j;
    float bn = (n < FFD) ? pb2[n] : 0.f;
    #pragma unroll
    for (int i=0;i<4;i++){
      float v = (n < FFD) ? fmaxf(acc[i][j] + bn, 0.f) : 0.f;
      z2T[n*68 + pg*4 + i] = v;
    }
  }
  __syncthreads();
  if (tid < 256) {
    int p = tid >> 2, c = tid & 3;
    float a = pb3[c];
    for (int k=0;k<FFD;k++) a = fmaf(z2T[k*68 + p], pw3[c*FFD + k], a);
    zf[tid] = a;
  }
  __syncthreads();
  if (tid < 64) {
    float z0 = zf[tid*4], z1 = zf[tid*4+1], z2 = zf[tid*4+2], z3 = zf[tid*4+3];
    float m = fmaxf(fmaxf(z0,z1), fmaxf(z2,z3));
    float e0 = expf(z0-m), e1 = expf(z1-m), e2 = expf(z2-m), e3 = expf(z3-m);
    float inv = 1.f/(e0+e1+e2+e3);
    float4 o4 = make_float4(e0*inv, e1*inv, e2*inv, e3*inv);
    *(float4*)&cp[(size_t)((b*4096 + ti*64 + tid))*4] = o4;
  }
}

// ---------------- launch ----------------
extern "C" void kernel_launch(void* const* d_in, const int* in_sizes, int n_in,
                              void* d_out, int out_size, void* d_ws, size_t ws_size,
                              hipStream_t stream) {
  const float* x    = (const float*)d_in[0];
  const float* WihF = (const float*)d_in[1];
  const float* WhhF = (const float*)d_in[2];
  const float* bihF = (const float*)d_in[3];
  const float* bhhF = (const float*)d_in[4];
  const float* WihB = (const float*)d_in[5];
  const float* WhhB = (const float*)d_in[6];
  const float* bihB = (const float*)d_in[7];
  const float* bhhB = (const float*)d_in[8];
  const float* wemb = (const float*)d_in[9];
  const float* demb = (const float*)d_in[10];
  const float* sw1  = (const float*)d_in[11];
  const float* sb1  = (const float*)d_in[12];
  const float* sw2  = (const float*)d_in[13];
  const float* sb2  = (const float*)d_in[14];
  const float* sw3  = (const float*)d_in[15];
  const float* sb3  = (const float*)d_in[16];
  const float* pw1  = (const float*)d_in[17];
  const float* pb1  = (const float*)d_in[18];
  const float* pw2  = (const float*)d_in[19];
  const float* pb2  = (const float*)d_in[20];
  const float* pw3  = (const float*)d_in[21];
  const float* pb3  = (const float*)d_in[22];

  uint8_t* wsb = (uint8_t*)d_ws;
  unsigned long long* hexch = (unsigned long long*)(wsb + 8192); // [2][8][320] u64 = 40 KB
  float* xg   = (float*)(wsb + 131072);            // [2][128][1200][8] = 2457600 f
  float* outh = xg   + 2457600;                    // [8][128][600]     = 614400 f
  float* UV   = outh + 614400;                     // [1024][300]       = 307200 f
  float* wcst = UV   + 307200;                     // [6][150]          = 900 f
  float* Zd   = wcst + 900;                        // [256][150]        = 38400 f
  float* ZTO  = Zd   + 38400;                      // [1024][150]       = 153600 f
  int*  idxw  = (int*)(ZTO + 153600);              // [2][8][64]        = 1024 i

  float* o   = (float*)d_out;
  float* spO = o;              // [8][630][3]  = 15120
  float* cpO = o + 15120;      // [8][4096][4] = 131072
  float* tO  = o + 146192;     // [8][64]
  float* oO  = o + 146704;     // [8][64]

  k_xg      <<<dim3(19,16,2), 256, 0, stream>>>(x, WihF, bihF, bhhF, WihB, bihB, bhhB, xg, hexch);
  k_lstm    <<<dim3(2*WPD), 320, 0, stream>>>(WhhF, WhhB, xg, hexch, outh);
  k_uv      <<<dim3(32,1,2), 320, 0, stream>>>(outh, sw1, UV);
  k_const   <<<dim3(262), 160, 0, stream>>>(sw1, wemb, wcst, pw1, demb, Zd);
  k_spanhead<<<dim3(10,8), 320, 0, stream>>>(UV, wcst, sb1, sw2, sb2, sw3, sb3, spO);
  k_topk    <<<dim3(16),  64, 0, stream>>>(spO, tO, oO, idxw);
  k_zto     <<<dim3(64),  320, 0, stream>>>(outh, wemb, pw1, idxw, ZTO);
  k_pairhead<<<dim3(64,8), 320, 0, stream>>>(ZTO, Zd, pb1, pw2, pb2, pw3, pb3, idxw, cpO);
}

// Round 5
// 1210.369 us; speedup vs baseline: 1.4663x; 1.1321x over previous
//
#include <hip/hip_runtime.h>
#include <stdint.h>
#include <stddef.h>

// ---------------- problem constants ----------------
#define BB   8
#define LL   128
#define DD   768
#define HH   300
#define G4   1200     // 4*H
#define NSP  630      // number of spans
#define FFD  150
#define NZK  64       // top-k

// LSTM persistent-kernel geometry: 60 WGs/dir, 5 h-rows/WG (j = wave id),
// 16 k-segments of 20 floats
#define WPD  60
#define JC   5

__device__ __forceinline__ float sigm(float x){ return 1.0f/(1.0f+expf(-x)); }

__device__ __forceinline__ void span_decode(int s, int& w, int& i){
  if      (s < 128){ w=1; i=s; }
  else if (s < 255){ w=2; i=s-128; }
  else if (s < 381){ w=3; i=s-255; }
  else if (s < 506){ w=4; i=s-381; }
  else             { w=5; i=s-506; }
}

__device__ __forceinline__ uint64_t shfl_xor_u64(uint64_t v, int m){
  uint32_t lo = (uint32_t)v, hi = (uint32_t)(v >> 32);
  lo = (uint32_t)__shfl_xor((int)lo, m, 64);
  hi = (uint32_t)__shfl_xor((int)hi, m, 64);
  return ((uint64_t)hi << 32) | lo;
}

// ---------------- K1: xg = Wih @ x + bih + bhh  (both dirs) ----------------
// xg layout: [dir][t][1200][8].  Block (0,0,0) also clears the 120 step-tags
// (signed ints; 0xAA poison is negative so polls are poison-safe anyway).
__global__ __launch_bounds__(256) void k_xg(
    const float* __restrict__ x,
    const float* __restrict__ WihF, const float* __restrict__ bihF, const float* __restrict__ bhhF,
    const float* __restrict__ WihB, const float* __restrict__ bihB, const float* __restrict__ bhhB,
    float* __restrict__ xg, int* __restrict__ tags)
{
  if (blockIdx.x==0 && blockIdx.y==0 && blockIdx.z==0) {
    for (int i = threadIdx.x; i < 2*60*32; i += 256)
      __hip_atomic_store(&tags[i], 0, __ATOMIC_RELAXED, __HIP_MEMORY_SCOPE_AGENT);
  }
  const int dir = blockIdx.z;
  const float* Wih = dir ? WihB : WihF;
  const float* bi  = dir ? bihB : bihF;
  const float* bh  = dir ? bhhB : bhhF;
  const int r0 = blockIdx.x * 64;
  const int n0 = blockIdx.y * 64;   // n = t*8 + b
  __shared__ __align__(16) float As[16*68];
  __shared__ __align__(16) float Bs[16*68];
  const int tid = threadIdx.x;
  const int rl = tid >> 2, kq = tid & 3;
  const int tx = tid & 15, ty = tid >> 4;
  float acc[4][4] = {};
  for (int k0 = 0; k0 < DD; k0 += 16) {
    float4 a4 = make_float4(0.f,0.f,0.f,0.f);
    int ra = r0 + rl;
    if (ra < G4) a4 = *(const float4*)&Wih[ra*DD + k0 + kq*4];
    As[(kq*4+0)*68 + rl] = a4.x;
    As[(kq*4+1)*68 + rl] = a4.y;
    As[(kq*4+2)*68 + rl] = a4.z;
    As[(kq*4+3)*68 + rl] = a4.w;
    int n = n0 + rl; int tt = n >> 3, bb = n & 7;
    float4 b4 = *(const float4*)&x[(bb*LL + tt)*DD + k0 + kq*4];
    Bs[(kq*4+0)*68 + rl] = b4.x;
    Bs[(kq*4+1)*68 + rl] = b4.y;
    Bs[(kq*4+2)*68 + rl] = b4.z;
    Bs[(kq*4+3)*68 + rl] = b4.w;
    __syncthreads();
    #pragma unroll
    for (int kk = 0; kk < 16; ++kk) {
      float4 av = *(const float4*)&As[kk*68 + tx*4];
      float4 bv = *(const float4*)&Bs[kk*68 + ty*4];
      float a_[4] = {av.x,av.y,av.z,av.w};
      float b_[4] = {bv.x,bv.y,bv.z,bv.w};
      #pragma unroll
      for (int i=0;i<4;i++)
        #pragma unroll
        for (int j=0;j<4;j++)
          acc[i][j] = fmaf(a_[i], b_[j], acc[i][j]);
    }
    __syncthreads();
  }
  #pragma unroll
  for (int i=0;i<4;i++){
    int r = r0 + tx*4 + i;
    if (r >= G4) continue;
    float bias = bi[r] + bh[r];
    #pragma unroll
    for (int j=0;j<4;j++){
      int n = n0 + ty*4 + j; int tt = n>>3, bb = n&7;
      xg[((dir*LL + tt)*G4 + r)*8 + bb] = acc[i][j] + bias;
    }
  }
}

// ---------------- K2: persistent bidirectional LSTM ----------------
// 120 wg (60/dir). Wave w of a WG owns h-index j = wid*5+w; Whh slice in regs.
// Readiness: per-producer tag line (posted AFTER __syncthreads, whose
// vmcnt(0) drain orders it behind the h stores). Wave0 polls 60 tags,
// relays via LDS flag. Data: one-shot bulk read of the 9.7KB h block with
// global_load_dwordx4 sc0 sc1 (MALL-coherent).
// RACE FIX vs R4: hex is DOUBLE-BUFFERED by step parity. Producer writes
// h(t+1) into parity (t+1)&1; consumer at t reads parity t&1. A producer
// re-enters a parity (t+2) only after the global tag check for t+1 passed,
// i.e. after every WG finished its step-t read — overwrite race closed.
__global__ __launch_bounds__(320) void k_lstm(
    const float* __restrict__ WhhF, const float* __restrict__ WhhB,
    const float* __restrict__ xg,
    float* __restrict__ hexf,           // [2 parity][2 dir][8][304] floats
    int* __restrict__ tags,             // [2][60] stride-32 ints
    float* __restrict__ out)            // [b][t][600]
{
  const int wg  = blockIdx.x;
  const int dir = wg / WPD;
  const int wid = wg - dir*WPD;
  const int j0  = wid * JC;
  const float* Whh = dir ? WhhB : WhhF;
  float* hex0 = hexf + (size_t)dir*2432;       // parity 0 base
  int* tg = tags + dir*60*32;

  __shared__ __align__(16) float hls[8*304 + 16];
  __shared__ int hready;

  const int tid  = threadIdx.x;
  const int wv   = tid >> 6;        // wave id = local j
  const int lane = tid & 63;
  const int rl   = lane >> 4;       // gate 0..3
  const int s    = lane & 15;       // k-segment (20 floats)
  const int Rabs = rl*HH + j0 + wv;
  const int bb   = s & 7;

  // register-resident Whh slice: 20 floats (5 float4) per thread
  float4 w4[5];
  #pragma unroll
  for (int q=0;q<5;q++){
    int k = s*20 + q*4;
    if (k + 3 < HH) w4[q] = *(const float4*)&Whh[(size_t)Rabs*HH + k];
    else            w4[q] = make_float4(0.f,0.f,0.f,0.f);
  }
  float creg = 0.f;                 // cell state, valid on lanes<8 (b=lane)
  if (tid == 0) hready = 0;
  {
    float4* h4 = (float4*)hls;      // zeros for t=0 (incl. pads)
    for (int i = tid; i < 612; i += 320) h4[i] = make_float4(0.f,0.f,0.f,0.f);
  }
  __syncthreads();

  float xg_c = xg[((size_t)(dir*LL + (dir ? LL-1 : 0))*G4 + Rabs)*8 + bb];

  for (int t = 0; t < LL; ++t) {
    const int tOrig = dir ? (LL-1 - t) : t;
    // prefetch next step's xg (overlaps poll/read latency)
    float xg_n = 0.f;
    if (t+1 < LL) {
      int tO2 = dir ? (LL-2 - t) : (t+1);
      xg_n = xg[((size_t)(dir*LL + tO2)*G4 + Rabs)*8 + bb];
    }
    if (t > 0) {
      // readiness: wave0 polls 60 tag lines; others spin on LDS flag
      if (wv == 0) {
        if (lane < 60) {
          while (__hip_atomic_load(&tg[lane*32], __ATOMIC_RELAXED,
                                   __HIP_MEMORY_SCOPE_AGENT) < t)
            __builtin_amdgcn_s_sleep(1);
        }
        if (lane == 0) ((volatile int*)&hready)[0] = t;
      } else {
        while (((volatile int*)&hready)[0] < t) __builtin_amdgcn_s_sleep(1);
      }
      // one-shot bulk read from parity t&1: 608 float4, MALL-coherent
      if (tid < 304) {
        const float* p0 = hex0 + (size_t)(t&1)*4864 + tid*8;
        float4 v0, v1;
        asm volatile(
          "global_load_dwordx4 %0, %2, off sc0 sc1\n\t"
          "global_load_dwordx4 %1, %3, off sc0 sc1\n\t"
          "s_waitcnt vmcnt(0)"
          : "=v"(v0), "=v"(v1)
          : "v"(p0), "v"(p0 + 4)
          : "memory");
        float4* d = (float4*)&hls[tid*8];
        d[0] = v0; d[1] = v1;
      }
    }
    __syncthreads();                          // B1: hls ready
    // partial dot products (4 rows/wave share each LDS word -> broadcast)
    float p[8];
    {
      const float4* h4 = (const float4*)hls;
      #pragma unroll
      for (int b=0;b<8;b++){
        const float4* hb = h4 + b*76 + s*5;   // 304 floats = 76 f4 per row
        float ax=0.f, ay=0.f, az=0.f, aw=0.f;
        #pragma unroll
        for (int q=0;q<5;q++){
          float4 hv = hb[q];
          ax = fmaf(w4[q].x, hv.x, ax);
          ay = fmaf(w4[q].y, hv.y, ay);
          az = fmaf(w4[q].z, hv.z, az);
          aw = fmaf(w4[q].w, hv.w, aw);
        }
        p[b] = (ax+ay)+(az+aw);
      }
    }
    // butterfly reduce-scatter over the 16 s-lanes
    #pragma unroll
    for (int b=0;b<8;b++) p[b] += __shfl_xor(p[b], 8, 64);
    float q4[4];
    #pragma unroll
    for (int b=0;b<4;b++){
      float mine = (s&4) ? p[b+4] : p[b];
      float oth  = (s&4) ? p[b]   : p[b+4];
      q4[b] = mine + __shfl_xor(oth, 4, 64);
    }
    float q2[2];
    #pragma unroll
    for (int b=0;b<2;b++){
      float mine = (s&2) ? q4[b+2] : q4[b];
      float oth  = (s&2) ? q4[b]   : q4[b+2];
      q2[b] = mine + __shfl_xor(oth, 2, 64);
    }
    float gv;
    {
      float mine = (s&1) ? q2[1] : q2[0];
      float oth  = (s&1) ? q2[0] : q2[1];
      gv = mine + __shfl_xor(oth, 1, 64) + xg_c;  // valid on s<8 (b=s)
    }
    // gather the 4 gates of (j=wv, b) in-wave
    {
      int bsel = lane & 7;
      float g_i = __shfl(gv,      bsel, 64);
      float g_f = __shfl(gv, 16 + bsel, 64);
      float g_g = __shfl(gv, 32 + bsel, 64);
      float g_o = __shfl(gv, 48 + bsel, 64);
      if (lane < 8) {
        int b = lane;
        float ig = sigm(g_i), fg = sigm(g_f), gg = tanhf(g_g), og = sigm(g_o);
        creg = fg * creg + ig * gg;
        float h = og * tanhf(creg);
        out[((size_t)(b*LL + tOrig))*600 + dir*HH + j0 + wv] = h;
        if (t+1 < LL)
          __hip_atomic_store(&hex0[(size_t)((t+1)&1)*4864 + b*304 + j0 + wv], h,
                             __ATOMIC_RELAXED, __HIP_MEMORY_SCOPE_AGENT);
      }
    }
    __syncthreads();   // B2: compiler drains vmcnt(0) -> h stores visible
    if (t+1 < LL && tid == 0)
      __hip_atomic_store(&tg[wid*32], t+1,
                         __ATOMIC_RELAXED, __HIP_MEMORY_SCOPE_AGENT);
    xg_c = xg_n;
  }
}

// ---------------- K3a: U/V partial span projections ----------------
// UV[row][half*150+n] = sum_k sw1[n][half*600+k] * out[row][k],  row = b*128+l
__global__ __launch_bounds__(320) void k_uv(
    const float* __restrict__ out, const float* __restrict__ sw1, float* __restrict__ UV)
{
  const int half = blockIdx.z;
  const int row0 = blockIdx.x * 32;
  __shared__ float As[16*36];
  __shared__ __align__(16) float Wt[16*172];
  const int tid = threadIdx.x;
  const int pg = tid / 20, ng = tid - (tid/20)*20;
  float acc[2][8] = {};
  for (int k0 = 0; k0 < 600; k0 += 16) {
    for (int idx = tid; idx < 512; idx += 320) {
      int p = idx >> 4, kk = idx & 15;
      int k = k0 + kk;
      As[kk*36 + p] = (k < 600) ? out[(row0 + p)*600 + k] : 0.f;
    }
    for (int idx = tid; idx < 16*160; idx += 320) {
      int n = idx >> 4, kk = idx & 15;
      int k = k0 + kk;
      Wt[kk*172 + n] = (n < FFD && k < 600) ? sw1[n*1220 + half*600 + k] : 0.f;
    }
    __syncthreads();
    #pragma unroll
    for (int kk=0;kk<16;kk++){
      float2 a2 = *(const float2*)&As[kk*36 + pg*2];
      float4 w0 = *(const float4*)&Wt[kk*172 + ng*8];
      float4 w1 = *(const float4*)&Wt[kk*172 + ng*8 + 4];
      float a_[2] = {a2.x, a2.y};
      float w_[8] = {w0.x,w0.y,w0.z,w0.w,w1.x,w1.y,w1.z,w1.w};
      #pragma unroll
      for (int i=0;i<2;i++)
        #pragma unroll
        for (int j=0;j<8;j++)
          acc[i][j] = fmaf(a_[i], w_[j], acc[i][j]);
    }
    __syncthreads();
  }
  #pragma unroll
  for (int i=0;i<2;i++){
    int row = row0 + pg*2 + i;
    #pragma unroll
    for (int j=0;j<8;j++){
      int n = ng*8 + j;
      if (n < FFD) UV[row*300 + half*FFD + n] = acc[i][j];
    }
  }
}

// ---------------- K3w+K5d merged: width-emb & dist-emb partials ----------------
__global__ __launch_bounds__(160) void k_const(
    const float* __restrict__ sw1, const float* __restrict__ wemb, float* __restrict__ wcst,
    const float* __restrict__ pw1, const float* __restrict__ demb, float* __restrict__ Zd)
{
  int n = threadIdx.x;
  if (n >= FFD) return;
  if (blockIdx.x < 6) {
    int w = blockIdx.x;
    float a = 0.f;
    for (int k=0;k<20;k++) a = fmaf(sw1[n*1220 + 1200 + k], wemb[w*20 + k], a);
    wcst[w*FFD + n] = a;
  } else {
    int d = blockIdx.x - 6;
    float a = 0.f;
    for (int k=0;k<128;k++) a = fmaf(pw1[n*2568 + 2440 + k], demb[d*128 + k], a);
    Zd[d*FFD + n] = a;
  }
}

// ---------------- K3b: span head (z1 combine -> layer2 -> layer3 -> softmax) ----------------
__global__ __launch_bounds__(320) void k_spanhead(
    const float* __restrict__ UV, const float* __restrict__ wcst,
    const float* __restrict__ sb1,
    const float* __restrict__ sw2, const float* __restrict__ sb2,
    const float* __restrict__ sw3, const float* __restrict__ sb3,
    float* __restrict__ sp)
{
  const int b  = blockIdx.y;
  const int s0 = blockIdx.x * 64;
  __shared__ __align__(16) float z1T[160*68];
  __shared__ __align__(16) float z2T[160*68];
  __shared__ __align__(16) float Wt[16*172];
  __shared__ float zf[256];
  __shared__ int sI[64], sJ[64], sW[64];
  const int tid = threadIdx.x;
  if (tid < 64) {
    int s = s0 + tid; int w = 1, i0 = 0;
    if (s < NSP) span_decode(s, w, i0);
    sI[tid] = i0; sJ[tid] = i0 + w - 1; sW[tid] = w;
  }
  __syncthreads();
  for (int idx = tid; idx < 64*160; idx += 320) {
    int p = idx / 160, k = idx - p*160;
    float v = 0.f;
    if (k < FFD && (s0 + p) < NSP) {
      v = UV[(b*LL + sI[p])*300 + k] + UV[(b*LL + sJ[p])*300 + FFD + k]
        + wcst[sW[p]*FFD + k] + sb1[k];
      v = fmaxf(v, 0.f);
    }
    z1T[k*68 + p] = v;
  }
  const int pg = tid / 20, ng = tid - (tid/20)*20;
  float acc[4][8] = {};
  for (int kt = 0; kt < 10; ++kt) {
    __syncthreads();
    for (int idx = tid; idx < 16*160; idx += 320) {
      int n = idx >> 4, kk = idx & 15;
      int k = kt*16 + kk;
      Wt[kk*172 + n] = (n < FFD && k < FFD) ? sw2[n*FFD + k] : 0.f;
    }
    __syncthreads();
    #pragma unroll
    for (int kk = 0; kk < 16; ++kk) {
      float4 a4 = *(const float4*)&z1T[(kt*16+kk)*68 + pg*4];
      float4 w0 = *(const float4*)&Wt[kk*172 + ng*8];
      float4 w1 = *(const float4*)&Wt[kk*172 + ng*8 + 4];
      float a_[4] = {a4.x,a4.y,a4.z,a4.w};
      float w_[8] = {w0.x,w0.y,w0.z,w0.w,w1.x,w1.y,w1.z,w1.w};
      #pragma unroll
      for (int i=0;i<4;i++)
        #pragma unroll
        for (int j=0;j<8;j++)
          acc[i][j] = fmaf(a_[i], w_[j], acc[i][j]);
    }
  }
  __syncthreads();
  #pragma unroll
  for (int j=0;j<8;j++){
    int n = ng*8 + j;
    float bn = (n < FFD) ? sb2[n] : 0.f;
    #pragma unroll
    for (int i=0;i<4;i++){
      float v = (n < FFD) ? fmaxf(acc[i][j] + bn, 0.f) : 0.f;
      z2T[n*68 + pg*4 + i] = v;
    }
  }
  __syncthreads();
  if (tid < 256) {
    int p = tid >> 2, c = tid & 3;
    if (c < 3 && (s0 + p) < NSP) {
      float a = sb3[c];
      for (int k=0;k<FFD;k++) a = fmaf(z2T[k*68 + p], sw3[c*FFD + k], a);
      zf[p*4 + c] = a;
    }
  }
  __syncthreads();
  if (tid < 64 && (s0 + tid) < NSP) {
    float z0 = zf[tid*4], z1 = zf[tid*4+1], z2 = zf[tid*4+2];
    float m = fmaxf(z0, fmaxf(z1, z2));
    float e0 = expf(z0-m), e1 = expf(z1-m), e2 = expf(z2-m);
    float inv = 1.f/(e0+e1+e2);
    int s = s0 + tid;
    sp[(b*NSP + s)*3 + 0] = e0*inv;
    sp[(b*NSP + s)*3 + 1] = e1*inv;
    sp[(b*NSP + s)*3 + 2] = e2*inv;
  }
}

// ---------------- K4: deterministic top-64 (ties -> smaller index) ----------------
__global__ __launch_bounds__(64) void k_topk(
    const float* __restrict__ sp, float* __restrict__ outT, float* __restrict__ outO,
    int* __restrict__ idxw)
{
  const int cls = blockIdx.x >> 3;   // 0: aspect(col1), 1: opinion(col2)
  const int b   = blockIdx.x & 7;
  const int lane = threadIdx.x;
  uint64_t key[10];
  #pragma unroll
  for (int q=0;q<10;q++){
    int s = lane + q*64;
    uint32_t bits = 0u;
    if (s < NSP) bits = __float_as_uint(sp[(b*NSP + s)*3 + 1 + cls]);
    key[q] = ((uint64_t)bits << 32) | (uint32_t)(1023 - s);
  }
  float* dst = cls ? outO : outT;
  for (int r = 0; r < NZK; ++r) {
    uint64_t best = key[0];
    #pragma unroll
    for (int q=1;q<10;q++) best = key[q] > best ? key[q] : best;
    #pragma unroll
    for (int off = 32; off > 0; off >>= 1) {
      uint64_t o = shfl_xor_u64(best, off);
      best = o > best ? o : best;
    }
    int sWin = 1023 - (int)(best & 0xFFFFFFFFu);
    if ((sWin & 63) == lane) {
      int qw = sWin >> 6;
      #pragma unroll
      for (int q=0;q<10;q++) if (q == qw) key[q] = 0;
    }
    if (lane == 0) {
      dst[b*NZK + r] = (float)sWin;
      idxw[cls*512 + b*NZK + r] = sWin;
    }
  }
}

// ---------------- K5a: Zt/Zo partial pair projections over selected spans ----------------
__global__ __launch_bounds__(320) void k_zto(
    const float* __restrict__ out, const float* __restrict__ wemb,
    const float* __restrict__ pw1, const int* __restrict__ idxw,
    float* __restrict__ ZTO)
{
  const int wg = blockIdx.x;
  const int cls = wg >> 5;
  const int rem = wg & 31;
  const int b = rem >> 2;
  const int i0 = (rem & 3) * 16;
  __shared__ float As[16*20];
  __shared__ __align__(16) float Wt[16*172];
  __shared__ int sI[16], sJ[16], sW[16];
  const int tid = threadIdx.x;
  if (tid < 16) {
    int S = idxw[cls*512 + b*64 + i0 + tid];
    int w, i_; span_decode(S, w, i_);
    sI[tid] = i_; sJ[tid] = i_ + w - 1; sW[tid] = w;
  }
  const int pg = tid / 20, ng = tid - (tid/20)*20;
  float acc[8] = {};
  __syncthreads();
  for (int k0 = 0; k0 < 1232; k0 += 16) {
    if (tid < 256) {
      int p = tid >> 4, kk = tid & 15;
      int k = k0 + kk;
      float v = 0.f;
      if      (k < 600)  v = out[(b*LL + sI[p])*600 + k];
      else if (k < 1200) v = out[(b*LL + sJ[p])*600 + (k - 600)];
      else if (k < 1220) v = wemb[sW[p]*20 + (k - 1200)];
      As[kk*20 + p] = v;
    }
    for (int idx = tid; idx < 16*160; idx += 320) {
      int n = idx >> 4, kk = idx & 15;
      int k = k0 + kk;
      Wt[kk*172 + n] = (n < FFD && k < 1220) ? pw1[n*2568 + cls*1220 + k] : 0.f;
    }
    __syncthreads();
    #pragma unroll
    for (int kk=0;kk<16;kk++){
      float a = As[kk*20 + pg];
      float4 w0 = *(const float4*)&Wt[kk*172 + ng*8];
      float4 w1 = *(const float4*)&Wt[kk*172 + ng*8 + 4];
      acc[0] = fmaf(a, w0.x, acc[0]);
      acc[1] = fmaf(a, w0.y, acc[1]);
      acc[2] = fmaf(a, w0.z, acc[2]);
      acc[3] = fmaf(a, w0.w, acc[3]);
      acc[4] = fmaf(a, w1.x, acc[4]);
      acc[5] = fmaf(a, w1.y, acc[5]);
      acc[6] = fmaf(a, w1.z, acc[6]);
      acc[7] = fmaf(a, w1.w, acc[7]);
    }
    __syncthreads();
  }
  #pragma unroll
  for (int j=0;j<8;j++){
    int n = ng*8 + j;
    if (n < FFD) ZTO[(cls*512 + b*64 + i0 + pg)*FFD + n] = acc[j];
  }
}

// ---------------- K5b: pair head ----------------
__global__ __launch_bounds__(320) void k_pairhead(
    const float* __restrict__ ZTO, const float* __restrict__ Zd,
    const float* __restrict__ pb1,
    const float* __restrict__ pw2, const float* __restrict__ pb2,
    const float* __restrict__ pw3, const float* __restrict__ pb3,
    const int* __restrict__ idxw,
    float* __restrict__ cp)
{
  const int b  = blockIdx.y;
  const int ti = blockIdx.x;
  __shared__ __align__(16) float z1T[160*68];
  __shared__ __align__(16) float z2T[160*68];
  __shared__ __align__(16) float Wt[16*172];
  __shared__ float zf[256];
  __shared__ int oDist[64];
  const int tid = threadIdx.x;
  const int tS = idxw[b*64 + ti];
  int wT, iT; span_decode(tS, wT, iT);
  const int aT = iT, bT = iT + wT - 1;
  if (tid < 64) {
    int oS = idxw[512 + b*64 + tid];
    int wO, iO; span_decode(oS, wO, iO);
    int d1 = bT - iO;            if (d1 < 0) d1 = -d1;
    int d2 = aT - (iO + wO - 1); if (d2 < 0) d2 = -d2;
    oDist[tid] = d1 < d2 ? d1 : d2;
  }
  __syncthreads();
  const float* ZtRow = ZTO + (b*64 + ti)*FFD;
  for (int idx = tid; idx < 64*160; idx += 320) {
    int p = idx / 160, k = idx - p*160;
    float v = 0.f;
    if (k < FFD) {
      v = ZtRow[k] + ZTO[(512 + b*64 + p)*FFD + k] + Zd[oDist[p]*FFD + k] + pb1[k];
      v = fmaxf(v, 0.f);
    }
    z1T[k*68 + p] = v;
  }
  const int pg = tid / 20, ng = tid - (tid/20)*20;
  float acc[4][8] = {};
  for (int kt = 0; kt < 10; ++kt) {
    __syncthreads();
    for (int idx = tid; idx < 16*160; idx += 320) {
      int n = idx >> 4, kk = idx & 15;
      int k = kt*16 + kk;
      Wt[kk*172 + n] = (n < FFD && k < FFD) ? pw2[n*FFD + k] : 0.f;
    }
    __syncthreads();
    #pragma unroll
    for (int kk = 0; kk < 16; ++kk) {
      float4 a4 = *(const float4*)&z1T[(kt*16+kk)*68 + pg*4];
      float4 w0 = *(const float4*)&Wt[kk*172 + ng*8];
      float4 w1 = *(const float4*)&Wt[kk*172 + ng*8 + 4];
      float a_[4] = {a4.x,a4.y,a4.z,a4.w};
      float w_[8] = {w0.x,w0.y,w0.z,w0.w,w1.x,w1.y,w1.z,w1.w};
      #pragma unroll
      for (int i=0;i<4;i++)
        #pragma unroll
        for (int j=0;j<8;j++)
          acc[i][j] = fmaf(a_[i], w_[j], acc[i][j]);
    }
  }
  __syncthreads();
  #pragma unroll
  for (int j=0;j<8;j++){
    int n = ng*8 + j;
    float bn = (n < FFD) ? pb2[n] : 0.f;
    #pragma unroll
    for (int i=0;i<4;i++){
      float v = (n < FFD) ? fmaxf(acc[i][j] + bn, 0.f) : 0.f;
      z2T[n*68 + pg*4 + i] = v;
    }
  }
  __syncthreads();
  if (tid < 256) {
    int p = tid >> 2, c = tid & 3;
    float a = pb3[c];
    for (int k=0;k<FFD;k++) a = fmaf(z2T[k*68 + p], pw3[c*FFD + k], a);
    zf[tid] = a;
  }
  __syncthreads();
  if (tid < 64) {
    float z0 = zf[tid*4], z1 = zf[tid*4+1], z2 = zf[tid*4+2], z3 = zf[tid*4+3];
    float m = fmaxf(fmaxf(z0,z1), fmaxf(z2,z3));
    float e0 = expf(z0-m), e1 = expf(z1-m), e2 = expf(z2-m), e3 = expf(z3-m);
    float inv = 1.f/(e0+e1+e2+e3);
    float4 o4 = make_float4(e0*inv, e1*inv, e2*inv, e3*inv);
    *(float4*)&cp[(size_t)((b*4096 + ti*64 + tid))*4] = o4;
  }
}

// ---------------- launch ----------------
extern "C" void kernel_launch(void* const* d_in, const int* in_sizes, int n_in,
                              void* d_out, int out_size, void* d_ws, size_t ws_size,
                              hipStream_t stream) {
  const float* x    = (const float*)d_in[0];
  const float* WihF = (const float*)d_in[1];
  const float* WhhF = (const float*)d_in[2];
  const float* bihF = (const float*)d_in[3];
  const float* bhhF = (const float*)d_in[4];
  const float* WihB = (const float*)d_in[5];
  const float* WhhB = (const float*)d_in[6];
  const float* bihB = (const float*)d_in[7];
  const float* bhhB = (const float*)d_in[8];
  const float* wemb = (const float*)d_in[9];
  const float* demb = (const float*)d_in[10];
  const float* sw1  = (const float*)d_in[11];
  const float* sb1  = (const float*)d_in[12];
  const float* sw2  = (const float*)d_in[13];
  const float* sb2  = (const float*)d_in[14];
  const float* sw3  = (const float*)d_in[15];
  const float* sb3  = (const float*)d_in[16];
  const float* pw1  = (const float*)d_in[17];
  const float* pb1  = (const float*)d_in[18];
  const float* pw2  = (const float*)d_in[19];
  const float* pb2  = (const float*)d_in[20];
  const float* pw3  = (const float*)d_in[21];
  const float* pb3  = (const float*)d_in[22];

  uint8_t* wsb = (uint8_t*)d_ws;
  int*   tags  = (int*)wsb;                        // [2][60] stride-32 ints (15.4 KB)
  float* hexf  = (float*)(wsb + 16384);            // [2][2][8][304] floats (38.9 KB)
  float* xg    = (float*)(wsb + 131072);           // [2][128][1200][8] = 2457600 f
  float* outh  = xg   + 2457600;                   // [8][128][600]     = 614400 f
  float* UV    = outh + 614400;                    // [1024][300]       = 307200 f
  float* wcst  = UV   + 307200;                    // [6][150]          = 900 f
  float* Zd    = wcst + 900;                       // [256][150]        = 38400 f
  float* ZTO   = Zd   + 38400;                     // [1024][150]       = 153600 f
  int*  idxw   = (int*)(ZTO + 153600);             // [2][8][64]        = 1024 i

  float* o   = (float*)d_out;
  float* spO = o;              // [8][630][3]  = 15120
  float* cpO = o + 15120;      // [8][4096][4] = 131072
  float* tO  = o + 146192;     // [8][64]
  float* oO  = o + 146704;     // [8][64]

  k_xg      <<<dim3(19,16,2), 256, 0, stream>>>(x, WihF, bihF, bhhF, WihB, bihB, bhhB, xg, tags);
  k_lstm    <<<dim3(2*WPD), 320, 0, stream>>>(WhhF, WhhB, xg, hexf, tags, outh);
  k_uv      <<<dim3(32,1,2), 320, 0, stream>>>(outh, sw1, UV);
  k_const   <<<dim3(262), 160, 0, stream>>>(sw1, wemb, wcst, pw1, demb, Zd);
  k_spanhead<<<dim3(10,8), 320, 0, stream>>>(UV, wcst, sb1, sw2, sb2, sw3, sb3, spO);
  k_topk    <<<dim3(16),  64, 0, stream>>>(spO, tO, oO, idxw);
  k_zto     <<<dim3(64),  320, 0, stream>>>(outh, wemb, pw1, idxw, ZTO);
  k_pairhead<<<dim3(64,8), 320, 0, stream>>>(ZTO, Zd, pb1, pw2, pb2, pw3, pb3, idxw, cpO);
}